// Round 1
// baseline (237.007 us; speedup 1.0000x reference)
//
#include <hip/hip_runtime.h>
#include <hip/hip_bf16.h>

#define D_MODEL 1024
#define STATE_N 256
#define BATCH 4
#define SEQ_LEN 4096
#define M_TOTAL (BATCH * SEQ_LEN)   // 16384
#define NCHUNK 64
#define CHUNK (SEQ_LEN / NCHUNK)    // 64

typedef __attribute__((ext_vector_type(8))) short bf16x8;
typedef __attribute__((ext_vector_type(4))) float f32x4;

static __device__ inline short f2bf(float f) {
    union { float f; unsigned u; } v; v.f = f;
    unsigned r = v.u + 0x7FFFu + ((v.u >> 16) & 1u);
    return (short)(r >> 16);
}

// ---------------- GEMM1: Bu[m][n] = sum_d u[m][d] * Bw[n][d] ----------------
// A = u [16384 x 1024] row-major fp32, B = Bw [256 x 1024] row-major fp32.
// Per-wave 32x32 output tile (2x2 fragments of 16x16x32 MFMA).
__global__ __launch_bounds__(256) void gemm_bu(const float* __restrict__ u,
                                               const float* __restrict__ Bw,
                                               float* __restrict__ Bu) {
    const int lane = threadIdx.x & 63;
    const int wave = threadIdx.x >> 6;
    const int lr = lane & 15;   // row (A) / col (B) within fragment
    const int kq = lane >> 4;   // k-quad: k = kq*8 + j
    const int rbase = blockIdx.x * 128 + wave * 32;
    const int cbase = blockIdx.y * 32;

    f32x4 acc00 = {0,0,0,0}, acc01 = {0,0,0,0}, acc10 = {0,0,0,0}, acc11 = {0,0,0,0};

    const float* ua0 = u  + (size_t)(rbase + lr) * D_MODEL + kq * 8;
    const float* ua1 = ua0 + (size_t)16 * D_MODEL;
    const float* bb0 = Bw + (size_t)(cbase + lr) * D_MODEL + kq * 8;
    const float* bb1 = bb0 + (size_t)16 * D_MODEL;

    for (int k0 = 0; k0 < D_MODEL; k0 += 32) {
        bf16x8 a0, a1, b0, b1;
        #pragma unroll
        for (int j = 0; j < 8; ++j) {
            a0[j] = f2bf(ua0[k0 + j]);
            a1[j] = f2bf(ua1[k0 + j]);
            b0[j] = f2bf(bb0[k0 + j]);
            b1[j] = f2bf(bb1[k0 + j]);
        }
        acc00 = __builtin_amdgcn_mfma_f32_16x16x32_bf16(a0, b0, acc00, 0, 0, 0);
        acc01 = __builtin_amdgcn_mfma_f32_16x16x32_bf16(a0, b1, acc01, 0, 0, 0);
        acc10 = __builtin_amdgcn_mfma_f32_16x16x32_bf16(a1, b0, acc10, 0, 0, 0);
        acc11 = __builtin_amdgcn_mfma_f32_16x16x32_bf16(a1, b1, acc11, 0, 0, 0);
    }

    // C/D layout: col = lane&15, row = (lane>>4)*4 + reg  [verified m89/m91]
    const int orow = rbase + kq * 4;
    #pragma unroll
    for (int i = 0; i < 4; ++i) {
        Bu[(size_t)(orow + i)      * STATE_N + cbase + lr]      = acc00[i];
        Bu[(size_t)(orow + i)      * STATE_N + cbase + 16 + lr] = acc01[i];
        Bu[(size_t)(orow + 16 + i) * STATE_N + cbase + lr]      = acc10[i];
        Bu[(size_t)(orow + 16 + i) * STATE_N + cbase + 16 + lr] = acc11[i];
    }
}

// ---------------- Scan pass 1: per-chunk local scan (in-place) ----------------
__global__ void scan_local(float* __restrict__ hloc,
                           const float* __restrict__ log_lambda,
                           float* __restrict__ ends) {
    const int n = threadIdx.x;              // 0..255
    const int c = blockIdx.x % NCHUNK;
    const int b = blockIdx.x / NCHUNK;
    const float lam = 1.0f / (1.0f + expf(-log_lambda[n]));
    float h = 0.0f;
    size_t idx = ((size_t)(b * SEQ_LEN + c * CHUNK)) * STATE_N + n;
    #pragma unroll 4
    for (int i = 0; i < CHUNK; ++i) {
        h = lam * h + hloc[idx];
        hloc[idx] = h;
        idx += STATE_N;
    }
    ends[(size_t)blockIdx.x * STATE_N + n] = h;
}

// ---------------- Scan pass 2: carry scan across chunks ----------------
__global__ void scan_carry(const float* __restrict__ ends,
                           const float* __restrict__ log_lambda,
                           float* __restrict__ carries) {
    const int t = threadIdx.x;              // 0..1023
    const int n = t & (STATE_N - 1);
    const int b = t >> 8;
    const float lam = 1.0f / (1.0f + expf(-log_lambda[n]));
    const float lamC = powf(lam, (float)CHUNK);
    float carry = 0.0f;
    for (int c = 0; c < NCHUNK; ++c) {
        size_t o = ((size_t)(b * NCHUNK + c)) * STATE_N + n;
        carries[o] = carry;
        carry = lamC * carry + ends[o];
    }
}

// ---------------- Scan pass 3: add carries, convert to bf16 ----------------
__global__ void scan_fix(const float* __restrict__ hloc,
                         const float* __restrict__ log_lambda,
                         const float* __restrict__ carries,
                         short* __restrict__ hbf) {
    const int n = threadIdx.x;
    const int c = blockIdx.x % NCHUNK;
    const int b = blockIdx.x / NCHUNK;
    const float lam = 1.0f / (1.0f + expf(-log_lambda[n]));
    const float carry = carries[(size_t)blockIdx.x * STATE_N + n];
    float f = lam;
    size_t idx = ((size_t)(b * SEQ_LEN + c * CHUNK)) * STATE_N + n;
    #pragma unroll 4
    for (int i = 0; i < CHUNK; ++i) {
        float h = hloc[idx] + f * carry;
        hbf[idx] = f2bf(h);
        f *= lam;
        idx += STATE_N;
    }
}

// ---------------- GEMM2: y[m][d] = sum_n h[m][n] * Cw[d][n] + D[d]*u[m][d] ----------------
// A = h_bf16 [16384 x 256] row-major, B = Cw [1024 x 256] row-major fp32.
__global__ __launch_bounds__(256) void gemm_y(const short* __restrict__ hbf,
                                              const float* __restrict__ Cw,
                                              const float* __restrict__ u,
                                              const float* __restrict__ Dv,
                                              float* __restrict__ y) {
    const int lane = threadIdx.x & 63;
    const int wave = threadIdx.x >> 6;
    const int lr = lane & 15;
    const int kq = lane >> 4;
    const int rbase = blockIdx.x * 128 + wave * 32;
    const int cbase = blockIdx.y * 32;

    f32x4 acc00 = {0,0,0,0}, acc01 = {0,0,0,0}, acc10 = {0,0,0,0}, acc11 = {0,0,0,0};

    const short* ha0 = hbf + (size_t)(rbase + lr) * STATE_N + kq * 8;
    const short* ha1 = ha0 + (size_t)16 * STATE_N;
    const float* cb0 = Cw  + (size_t)(cbase + lr) * STATE_N + kq * 8;
    const float* cb1 = cb0 + (size_t)16 * STATE_N;

    #pragma unroll
    for (int k0 = 0; k0 < STATE_N; k0 += 32) {
        bf16x8 a0 = *reinterpret_cast<const bf16x8*>(ha0 + k0);
        bf16x8 a1 = *reinterpret_cast<const bf16x8*>(ha1 + k0);
        bf16x8 b0, b1;
        #pragma unroll
        for (int j = 0; j < 8; ++j) {
            b0[j] = f2bf(cb0[k0 + j]);
            b1[j] = f2bf(cb1[k0 + j]);
        }
        acc00 = __builtin_amdgcn_mfma_f32_16x16x32_bf16(a0, b0, acc00, 0, 0, 0);
        acc01 = __builtin_amdgcn_mfma_f32_16x16x32_bf16(a0, b1, acc01, 0, 0, 0);
        acc10 = __builtin_amdgcn_mfma_f32_16x16x32_bf16(a1, b0, acc10, 0, 0, 0);
        acc11 = __builtin_amdgcn_mfma_f32_16x16x32_bf16(a1, b1, acc11, 0, 0, 0);
    }

    const int orow = rbase + kq * 4;
    const int col0 = cbase + lr;
    const int col1 = cbase + 16 + lr;
    const float d0 = Dv[col0];
    const float d1 = Dv[col1];
    #pragma unroll
    for (int i = 0; i < 4; ++i) {
        {
            size_t o = (size_t)(orow + i) * D_MODEL;
            y[o + col0] = acc00[i] + d0 * u[o + col0];
            y[o + col1] = acc01[i] + d1 * u[o + col1];
        }
        {
            size_t o = (size_t)(orow + 16 + i) * D_MODEL;
            y[o + col0] = acc10[i] + d0 * u[o + col0];
            y[o + col1] = acc11[i] + d1 * u[o + col1];
        }
    }
}

extern "C" void kernel_launch(void* const* d_in, const int* in_sizes, int n_in,
                              void* d_out, int out_size, void* d_ws, size_t ws_size,
                              hipStream_t stream) {
    const float* u  = (const float*)d_in[0];
    const float* ll = (const float*)d_in[1];
    const float* Bw = (const float*)d_in[2];
    const float* Cw = (const float*)d_in[3];
    const float* Dv = (const float*)d_in[4];
    float* y = (float*)d_out;

    char* ws = (char*)d_ws;
    float* Bu      = (float*)ws;                                         // 16 MB (also h_local in-place)
    short* hbf     = (short*)(ws + (size_t)M_TOTAL * STATE_N * 4);       // 8 MB
    float* ends    = (float*)(ws + (size_t)M_TOTAL * STATE_N * 6);      // 256 KB
    float* carries = ends + (size_t)BATCH * NCHUNK * STATE_N;           // 256 KB

    gemm_bu<<<dim3(M_TOTAL / 128, STATE_N / 32), 256, 0, stream>>>(u, Bw, Bu);
    scan_local<<<BATCH * NCHUNK, STATE_N, 0, stream>>>(Bu, ll, ends);
    scan_carry<<<1, BATCH * STATE_N, 0, stream>>>(ends, ll, carries);
    scan_fix<<<BATCH * NCHUNK, STATE_N, 0, stream>>>(Bu, ll, carries, hbf);
    gemm_y<<<dim3(M_TOTAL / 128, D_MODEL / 32), 256, 0, stream>>>(hbf, Cw, u, Dv, y);
}

// Round 2
// 112.715 us; speedup vs baseline: 2.1027x; 2.1027x over previous
//
#include <hip/hip_runtime.h>
#include <hip/hip_bf16.h>

#define D_MODEL 1024
#define STATE_N 256
#define BATCH 4
#define SEQ_LEN 4096
#define M_TOTAL (BATCH * SEQ_LEN)   // 16384
#define NCHUNK 128
#define CHUNK (SEQ_LEN / NCHUNK)    // 32

typedef __attribute__((ext_vector_type(8))) short bf16x8;
typedef __attribute__((ext_vector_type(4))) float f32x4;

static __device__ inline short f2bf(float f) {
    union { float f; unsigned u; } v; v.f = f;
    unsigned r = v.u + 0x7FFFu + ((v.u >> 16) & 1u);
    return (short)(r >> 16);
}

static __device__ inline float sigmoidf(float x) {
    return 1.0f / (1.0f + expf(-x));
}

#define GLOAD_LDS16(gp, lp)                                                     \
    __builtin_amdgcn_global_load_lds(                                           \
        (const __attribute__((address_space(1))) void*)(gp),                    \
        (__attribute__((address_space(3))) void*)(lp), 16, 0, 0)

// ---------------- Pass 0: fp32 -> bf16 conversion of u, B_w, C_w ----------------
__global__ void to_bf16_all(const float* __restrict__ u, const float* __restrict__ Bw,
                            const float* __restrict__ Cw, short* __restrict__ ubf,
                            short* __restrict__ Bwbf, short* __restrict__ Cwbf) {
    const long NU = (long)M_TOTAL * D_MODEL / 8;   // vec8 groups
    const long NW = (long)STATE_N * D_MODEL / 8;
    const long total = NU + 2 * NW;
    const long stride = (long)gridDim.x * blockDim.x;
    for (long i = (long)blockIdx.x * blockDim.x + threadIdx.x; i < total; i += stride) {
        const float* s; short* d; long j;
        if (i < NU)            { s = u;  d = ubf;  j = i; }
        else if (i < NU + NW)  { s = Bw; d = Bwbf; j = i - NU; }
        else                   { s = Cw; d = Cwbf; j = i - NU - NW; }
        const f32x4 v0 = *(const f32x4*)(s + j * 8);
        const f32x4 v1 = *(const f32x4*)(s + j * 8 + 4);
        bf16x8 r;
        #pragma unroll
        for (int t = 0; t < 4; ++t) { r[t] = f2bf(v0[t]); r[4 + t] = f2bf(v1[t]); }
        *(bf16x8*)(d + j * 8) = r;
    }
}

// ---------------- m97-style NT GEMM: C[M][NTOT] = A[M][K]bf16 * B[NTOT][K]bf16^T ----------------
// 128x128 block tile, 4 waves each 64x64 (4x4 frags of 16x16x32), BK=32,
// global_load_lds width-16 staging, fp32 accumulate.
// EPI: C[o] = acc + Dv[col] * u[o]   (gemm2 epilogue)
template <int KDIM, int NTOT, bool EPI>
__global__ __launch_bounds__(256) void gemm_nt(const short* __restrict__ A,
                                               const short* __restrict__ Bm,
                                               float* __restrict__ C,
                                               const float* __restrict__ u,
                                               const float* __restrict__ Dv) {
    __shared__ short As[128 * 32];   // [row][k] 64B per row
    __shared__ short Bs[128 * 32];
    const int tid = threadIdx.x;
    const int lane = tid & 63, wave = tid >> 6;
    const int lr = lane & 15, kq = lane >> 4;
    const int wr = wave >> 1, wc = wave & 1;
    const int arow = blockIdx.x * 128;
    const int bcol = blockIdx.y * 128;

    f32x4 acc[4][4] = {};

    for (int k0 = 0; k0 < KDIM; k0 += 32) {
        __syncthreads();   // previous tile's ds_reads done before overwrite
        #pragma unroll
        for (int c = 0; c < 2; ++c) {
            const int off = (c << 12) + (wave << 10) + (lane << 4);  // byte off in tile
            const int row = off >> 6;
            const int kb  = off & 63;
            GLOAD_LDS16((const char*)A  + ((size_t)(arow + row) * KDIM + k0) * 2 + kb,
                        (char*)As + (c << 12) + (wave << 10));
            GLOAD_LDS16((const char*)Bm + ((size_t)(bcol + row) * KDIM + k0) * 2 + kb,
                        (char*)Bs + (c << 12) + (wave << 10));
        }
        __syncthreads();   // staging complete (vmcnt drained by barrier)

        bf16x8 af[4], bfr[4];
        #pragma unroll
        for (int i = 0; i < 4; ++i) {
            af[i]  = *(const bf16x8*)((const char*)As + (((wr << 6) + (i << 4) + lr) << 6) + (kq << 4));
            bfr[i] = *(const bf16x8*)((const char*)Bs + (((wc << 6) + (i << 4) + lr) << 6) + (kq << 4));
        }
        #pragma unroll
        for (int i = 0; i < 4; ++i)
            #pragma unroll
            for (int j = 0; j < 4; ++j)
                acc[i][j] = __builtin_amdgcn_mfma_f32_16x16x32_bf16(af[i], bfr[j], acc[i][j], 0, 0, 0);
    }

    // C/D layout: col = lane&15, row = (lane>>4)*4 + reg   [verified m89/m91]
    const int orow = arow + (wr << 6) + (kq << 2);
    const int ocol = bcol + (wc << 6) + lr;
    #pragma unroll
    for (int i = 0; i < 4; ++i)
        #pragma unroll
        for (int j = 0; j < 4; ++j) {
            const int col = ocol + (j << 4);
            #pragma unroll
            for (int r = 0; r < 4; ++r) {
                const size_t o = (size_t)(orow + (i << 4) + r) * NTOT + col;
                float v = acc[i][j][r];
                if (EPI) v = fmaf(Dv[col], u[o], v);
                C[o] = v;
            }
        }
}

// ---------------- Scan pass 1: per-chunk end state only (no intermediate write) ----------------
__global__ void scan_ends(const float* __restrict__ Bu,
                          const float* __restrict__ log_lambda,
                          float* __restrict__ ends) {
    const int n = threadIdx.x;                  // 0..255
    const int c = blockIdx.x & (NCHUNK - 1);
    const int b = blockIdx.x >> 7;
    const float lam = sigmoidf(log_lambda[n]);
    float h = 0.0f;
    size_t idx = ((size_t)(b * SEQ_LEN + c * CHUNK)) * STATE_N + n;
    #pragma unroll
    for (int i = 0; i < CHUNK; ++i) { h = fmaf(lam, h, Bu[idx]); idx += STATE_N; }
    ends[(size_t)blockIdx.x * STATE_N + n] = h;
}

// ---------------- Scan pass 2: carry scan across chunks ----------------
__global__ void scan_carry(const float* __restrict__ ends,
                           const float* __restrict__ log_lambda,
                           float* __restrict__ carries) {
    const int t = threadIdx.x;                  // 0..1023
    const int n = t & (STATE_N - 1);
    const int b = t >> 8;
    const float lam = sigmoidf(log_lambda[n]);
    const float lamC = powf(lam, (float)CHUNK);
    float carry = 0.0f;
    for (int c = 0; c < NCHUNK; ++c) {
        const size_t o = ((size_t)(b * NCHUNK + c)) * STATE_N + n;
        carries[o] = carry;
        carry = fmaf(lamC, carry, ends[o]);
    }
}

// ---------------- Scan pass 3: full scan seeded by carry, write bf16 h ----------------
__global__ void scan_fix(const float* __restrict__ Bu,
                         const float* __restrict__ log_lambda,
                         const float* __restrict__ carries,
                         short* __restrict__ hbf) {
    const int n = threadIdx.x;
    const int c = blockIdx.x & (NCHUNK - 1);
    const int b = blockIdx.x >> 7;
    const float lam = sigmoidf(log_lambda[n]);
    float h = carries[(size_t)blockIdx.x * STATE_N + n];
    size_t idx = ((size_t)(b * SEQ_LEN + c * CHUNK)) * STATE_N + n;
    #pragma unroll
    for (int i = 0; i < CHUNK; ++i) {
        h = fmaf(lam, h, Bu[idx]);
        hbf[idx] = f2bf(h);
        idx += STATE_N;
    }
}

extern "C" void kernel_launch(void* const* d_in, const int* in_sizes, int n_in,
                              void* d_out, int out_size, void* d_ws, size_t ws_size,
                              hipStream_t stream) {
    const float* u  = (const float*)d_in[0];
    const float* ll = (const float*)d_in[1];
    const float* Bw = (const float*)d_in[2];
    const float* Cw = (const float*)d_in[3];
    const float* Dv = (const float*)d_in[4];
    float* y = (float*)d_out;

    char* ws = (char*)d_ws;
    size_t off = 0;
    short* ubf  = (short*)(ws + off); off += (size_t)M_TOTAL * D_MODEL * 2;   // 32 MB
    short* Bwbf = (short*)(ws + off); off += (size_t)STATE_N * D_MODEL * 2;   // 512 KB
    short* Cwbf = (short*)(ws + off); off += (size_t)D_MODEL * STATE_N * 2;   // 512 KB
    float* Bu   = (float*)(ws + off); off += (size_t)M_TOTAL * STATE_N * 4;   // 16 MB
    short* hbf  = (short*)(ws + off); off += (size_t)M_TOTAL * STATE_N * 2;   // 8 MB
    float* ends = (float*)(ws + off); off += (size_t)BATCH * NCHUNK * STATE_N * 4;
    float* carries = (float*)(ws + off);

    to_bf16_all<<<2048, 256, 0, stream>>>(u, Bw, Cw, ubf, Bwbf, Cwbf);
    gemm_nt<D_MODEL, STATE_N, false><<<dim3(M_TOTAL / 128, STATE_N / 128), 256, 0, stream>>>(
        ubf, Bwbf, Bu, nullptr, nullptr);
    scan_ends<<<BATCH * NCHUNK, STATE_N, 0, stream>>>(Bu, ll, ends);
    scan_carry<<<1, BATCH * STATE_N, 0, stream>>>(ends, ll, carries);
    scan_fix<<<BATCH * NCHUNK, STATE_N, 0, stream>>>(Bu, ll, carries, hbf);
    gemm_nt<STATE_N, D_MODEL, true><<<dim3(M_TOTAL / 128, D_MODEL / 128), 256, 0, stream>>>(
        hbf, Cwbf, y, u, Dv);
}

// Round 3
// 110.573 us; speedup vs baseline: 2.1434x; 1.0194x over previous
//
#include <hip/hip_runtime.h>

#define D_MODEL 1024
#define STATE_N 256
#define BATCH 4
#define SEQ_LEN 4096
#define M_TOTAL (BATCH * SEQ_LEN)   // 16384
#define NCHUNK 128
#define CHUNK (SEQ_LEN / NCHUNK)    // 32

typedef __attribute__((ext_vector_type(8))) short bf16x8;
typedef __attribute__((ext_vector_type(4))) short s16x4;
typedef __attribute__((ext_vector_type(4))) float f32x4;

static __device__ inline short f2bf(float f) {
    union { float f; unsigned u; } v; v.f = f;
    unsigned r = v.u + 0x7FFFu + ((v.u >> 16) & 1u);
    return (short)(r >> 16);
}
static __device__ inline float bf2f(short s) {
    union { unsigned u; float f; } v;
    v.u = ((unsigned)(unsigned short)s) << 16;
    return v.f;
}
static __device__ inline float sigmoidf(float x) { return 1.0f / (1.0f + expf(-x)); }

#define GLOAD_LDS16(gp, lp)                                                     \
    __builtin_amdgcn_global_load_lds(                                           \
        (const __attribute__((address_space(1))) void*)(gp),                    \
        (__attribute__((address_space(3))) void*)(lp), 16, 0, 0)

// ---------------- tiny pass: Bw, Cw fp32 -> bf16 ----------------
__global__ void to_bf16_w(const float* __restrict__ Bw, const float* __restrict__ Cw,
                          short* __restrict__ Bwbf, short* __restrict__ Cwbf) {
    const int NW = STATE_N * D_MODEL / 8;   // 32768 vec8 groups per matrix
    const int i = blockIdx.x * 256 + threadIdx.x;   // grid 256 -> 65536 == 2*NW
    const float* s; short* d; int j;
    if (i < NW) { s = Bw; d = Bwbf; j = i; } else { s = Cw; d = Cwbf; j = i - NW; }
    const f32x4 v0 = *(const f32x4*)(s + (size_t)j * 8);
    const f32x4 v1 = *(const f32x4*)(s + (size_t)j * 8 + 4);
    bf16x8 r;
    #pragma unroll
    for (int t = 0; t < 4; ++t) { r[t] = f2bf(v0[t]); r[4 + t] = f2bf(v1[t]); }
    *(bf16x8*)(d + (size_t)j * 8) = r;
}

// ---------------- GEMM1: Bu[m][n] = u[m][:] . Bw[n][:]  (fp32 A inline-cvt) ----------------
// BM=64, BN=128, BK=32. 4 waves as 2M x 2N, each 32x64 (2x4 frags).
// LDS layout [kq][row][8 bf16] -> conflict-free ds_read_b128.
// Swapped MFMA: lane&15 = m, (lane>>4)*4+r = n -> Bu store is 4 consecutive n (8B bf16).
__global__ __launch_bounds__(256) void gemm1(const float* __restrict__ u,
                                             const short* __restrict__ Bwbf,
                                             short* __restrict__ Bu) {
    __shared__ short As[64 * 32];    // 4KB: [kq][64 rows][8]
    __shared__ short Bs[128 * 32];   // 8KB: [kq][128 rows][8]
    const int tid = threadIdx.x;
    const int lane = tid & 63, wave = tid >> 6;
    const int lr = lane & 15, kq = lane >> 4;
    const int wr = wave >> 1, wc = wave & 1;
    const int arow = blockIdx.x * 64;
    const int bcol = blockIdx.y * 128;

    f32x4 acc[2][4] = {};

    // A staging: thread = slot (kq=wave, row=lane); 8 fp32 -> 8 bf16 (16B slot)
    const float* aptr = u + (size_t)(arow + lane) * D_MODEL + wave * 8;
    short* awr = As + tid * 8;

    for (int k0 = 0; k0 < D_MODEL; k0 += 32) {
        __syncthreads();
        #pragma unroll
        for (int c = 0; c < 2; ++c) {
            const int slot = c * 256 + tid;
            const int bkq = slot >> 7, brw = slot & 127;
            GLOAD_LDS16((const char*)Bwbf + ((size_t)(bcol + brw) * D_MODEL + k0 + bkq * 8) * 2,
                        (char*)Bs + (c << 12) + (wave << 10));
        }
        const f32x4 a0 = *(const f32x4*)(aptr + k0);
        const f32x4 a1 = *(const f32x4*)(aptr + k0 + 4);
        bf16x8 ar;
        #pragma unroll
        for (int t = 0; t < 4; ++t) { ar[t] = f2bf(a0[t]); ar[4 + t] = f2bf(a1[t]); }
        *(bf16x8*)awr = ar;     // ds_write_b128, linear per lane
        __syncthreads();

        bf16x8 af[2], bfr[4];
        #pragma unroll
        for (int i = 0; i < 2; ++i)
            af[i] = *(const bf16x8*)(As + kq * 512 + (wr * 32 + i * 16 + lr) * 8);
        #pragma unroll
        for (int j = 0; j < 4; ++j)
            bfr[j] = *(const bf16x8*)(Bs + kq * 1024 + (wc * 64 + j * 16 + lr) * 8);
        #pragma unroll
        for (int i = 0; i < 2; ++i)
            #pragma unroll
            for (int j = 0; j < 4; ++j)
                acc[i][j] = __builtin_amdgcn_mfma_f32_16x16x32_bf16(bfr[j], af[i], acc[i][j], 0, 0, 0);
    }

    #pragma unroll
    for (int i = 0; i < 2; ++i) {
        const int m = arow + wr * 32 + i * 16 + lr;
        #pragma unroll
        for (int j = 0; j < 4; ++j) {
            const int n = bcol + wc * 64 + j * 16 + kq * 4;
            s16x4 st;
            #pragma unroll
            for (int r = 0; r < 4; ++r) st[r] = f2bf(acc[i][j][r]);
            *(s16x4*)(Bu + (size_t)m * STATE_N + n) = st;
        }
    }
}

// ---------------- GEMM2: y[m][d] = h[m][:] . Cw[d][:] + D[d]*u[m][d] ----------------
// BM=128, BN=128, BK=32. 4 waves 2x2, each 64x64 (4x4 frags). Both operands bf16 via gload_lds.
__global__ __launch_bounds__(256) void gemm2(const short* __restrict__ hbf,
                                             const short* __restrict__ Cwbf,
                                             const float* __restrict__ u,
                                             const float* __restrict__ Dv,
                                             float* __restrict__ y) {
    __shared__ short As[128 * 32];   // 8KB
    __shared__ short Bs[128 * 32];   // 8KB
    const int tid = threadIdx.x;
    const int lane = tid & 63, wave = tid >> 6;
    const int lr = lane & 15, kq = lane >> 4;
    const int wr = wave >> 1, wc = wave & 1;
    const int arow = blockIdx.x * 128;
    const int bcol = blockIdx.y * 128;

    f32x4 acc[4][4] = {};

    for (int k0 = 0; k0 < STATE_N; k0 += 32) {
        __syncthreads();
        #pragma unroll
        for (int c = 0; c < 2; ++c) {
            const int slot = c * 256 + tid;
            const int skq = slot >> 7, srw = slot & 127;
            GLOAD_LDS16((const char*)hbf  + ((size_t)(arow + srw) * STATE_N + k0 + skq * 8) * 2,
                        (char*)As + (c << 12) + (wave << 10));
            GLOAD_LDS16((const char*)Cwbf + ((size_t)(bcol + srw) * STATE_N + k0 + skq * 8) * 2,
                        (char*)Bs + (c << 12) + (wave << 10));
        }
        __syncthreads();

        bf16x8 af[4], bfr[4];
        #pragma unroll
        for (int i = 0; i < 4; ++i)
            af[i]  = *(const bf16x8*)(As + kq * 1024 + (wr * 64 + i * 16 + lr) * 8);
        #pragma unroll
        for (int j = 0; j < 4; ++j)
            bfr[j] = *(const bf16x8*)(Bs + kq * 1024 + (wc * 64 + j * 16 + lr) * 8);
        #pragma unroll
        for (int i = 0; i < 4; ++i)
            #pragma unroll
            for (int j = 0; j < 4; ++j)
                acc[i][j] = __builtin_amdgcn_mfma_f32_16x16x32_bf16(bfr[j], af[i], acc[i][j], 0, 0, 0);
    }

    // lane&15 = m offset, kq*4+r = n offset -> f32x4 is 4 consecutive n: vector epilogue
    #pragma unroll
    for (int i = 0; i < 4; ++i) {
        const int m = arow + wr * 64 + i * 16 + lr;
        #pragma unroll
        for (int j = 0; j < 4; ++j) {
            const int n = bcol + wc * 64 + j * 16 + kq * 4;
            const size_t o = (size_t)m * D_MODEL + n;
            const f32x4 uv = *(const f32x4*)(u + o);
            const f32x4 dv = *(const f32x4*)(Dv + n);
            f32x4 rv;
            #pragma unroll
            for (int t = 0; t < 4; ++t) rv[t] = fmaf(dv[t], uv[t], acc[i][j][t]);
            *(f32x4*)(y + o) = rv;
        }
    }
}

// ---------------- Scan pass 1: per-chunk end state ----------------
__global__ void scan_ends(const short* __restrict__ Bu,
                          const float* __restrict__ log_lambda,
                          float* __restrict__ ends) {
    const int n = threadIdx.x;
    const int c = blockIdx.x & (NCHUNK - 1);
    const int b = blockIdx.x >> 7;
    const float lam = sigmoidf(log_lambda[n]);
    float h = 0.0f;
    size_t idx = ((size_t)(b * SEQ_LEN + c * CHUNK)) * STATE_N + n;
    #pragma unroll
    for (int i = 0; i < CHUNK; ++i) { h = fmaf(lam, h, bf2f(Bu[idx])); idx += STATE_N; }
    ends[(size_t)blockIdx.x * STATE_N + n] = h;
}

// ---------------- Scan pass 2: carry scan across chunks ----------------
__global__ void scan_carry(const float* __restrict__ ends,
                           const float* __restrict__ log_lambda,
                           float* __restrict__ carries) {
    const int t = threadIdx.x;                  // 0..1023
    const int n = t & (STATE_N - 1);
    const int b = t >> 8;
    const float lam = sigmoidf(log_lambda[n]);
    const float lamC = powf(lam, (float)CHUNK);
    float carry = 0.0f;
    for (int c = 0; c < NCHUNK; ++c) {
        const size_t o = ((size_t)(b * NCHUNK + c)) * STATE_N + n;
        carries[o] = carry;
        carry = fmaf(lamC, carry, ends[o]);
    }
}

// ---------------- Scan pass 3: seeded scan, write bf16 h ----------------
__global__ void scan_fix(const short* __restrict__ Bu,
                         const float* __restrict__ log_lambda,
                         const float* __restrict__ carries,
                         short* __restrict__ hbf) {
    const int n = threadIdx.x;
    const int c = blockIdx.x & (NCHUNK - 1);
    const int b = blockIdx.x >> 7;
    const float lam = sigmoidf(log_lambda[n]);
    float h = carries[(size_t)blockIdx.x * STATE_N + n];
    size_t idx = ((size_t)(b * SEQ_LEN + c * CHUNK)) * STATE_N + n;
    #pragma unroll
    for (int i = 0; i < CHUNK; ++i) {
        h = fmaf(lam, h, bf2f(Bu[idx]));
        hbf[idx] = f2bf(h);
        idx += STATE_N;
    }
}

extern "C" void kernel_launch(void* const* d_in, const int* in_sizes, int n_in,
                              void* d_out, int out_size, void* d_ws, size_t ws_size,
                              hipStream_t stream) {
    const float* u  = (const float*)d_in[0];
    const float* ll = (const float*)d_in[1];
    const float* Bw = (const float*)d_in[2];
    const float* Cw = (const float*)d_in[3];
    const float* Dv = (const float*)d_in[4];
    float* y = (float*)d_out;

    char* ws = (char*)d_ws;
    size_t off = 0;
    short* Bwbf = (short*)(ws + off); off += (size_t)STATE_N * D_MODEL * 2;     // 512 KB
    short* Cwbf = (short*)(ws + off); off += (size_t)D_MODEL * STATE_N * 2;     // 512 KB
    short* Bu   = (short*)(ws + off); off += (size_t)M_TOTAL * STATE_N * 2;     // 8 MB
    short* hbf  = (short*)(ws + off); off += (size_t)M_TOTAL * STATE_N * 2;     // 8 MB
    float* ends = (float*)(ws + off); off += (size_t)BATCH * NCHUNK * STATE_N * 4;
    float* carries = (float*)(ws + off);

    to_bf16_w<<<256, 256, 0, stream>>>(Bw, Cw, Bwbf, Cwbf);
    gemm1<<<dim3(M_TOTAL / 64, STATE_N / 128), 256, 0, stream>>>(u, Bwbf, Bu);
    scan_ends<<<BATCH * NCHUNK, STATE_N, 0, stream>>>(Bu, ll, ends);
    scan_carry<<<1, BATCH * STATE_N, 0, stream>>>(ends, ll, carries);
    scan_fix<<<BATCH * NCHUNK, STATE_N, 0, stream>>>(Bu, ll, carries, hbf);
    gemm2<<<dim3(M_TOTAL / 128, D_MODEL / 128), 256, 0, stream>>>(hbf, Cwbf, u, Dv, y);
}

// Round 4
// 102.473 us; speedup vs baseline: 2.3129x; 1.0791x over previous
//
#include <hip/hip_runtime.h>

#define D_MODEL 1024
#define STATE_N 256
#define BATCH 4
#define SEQ_LEN 4096
#define M_TOTAL (BATCH * SEQ_LEN)   // 16384
#define NCHUNK 128
#define CHUNK (SEQ_LEN / NCHUNK)    // 32

typedef __attribute__((ext_vector_type(8))) short bf16x8;
typedef __attribute__((ext_vector_type(4))) short s16x4;
typedef __attribute__((ext_vector_type(4))) float f32x4;

static __device__ inline short f2bf(float f) {
    union { float f; unsigned u; } v; v.f = f;
    unsigned r = v.u + 0x7FFFu + ((v.u >> 16) & 1u);
    return (short)(r >> 16);
}
static __device__ inline float bf2f(short s) {
    union { unsigned u; float f; } v;
    v.u = ((unsigned)(unsigned short)s) << 16;
    return v.f;
}
static __device__ inline float sigmoidf(float x) { return 1.0f / (1.0f + expf(-x)); }

#define GLOAD_LDS16(gp, lp)                                                     \
    __builtin_amdgcn_global_load_lds(                                           \
        (const __attribute__((address_space(1))) void*)(gp),                    \
        (__attribute__((address_space(3))) void*)(lp), 16, 0, 0)

// ---------------- tiny pass: Bw, Cw fp32 -> bf16 ----------------
__global__ void to_bf16_w(const float* __restrict__ Bw, const float* __restrict__ Cw,
                          short* __restrict__ Bwbf, short* __restrict__ Cwbf) {
    const int NW = STATE_N * D_MODEL / 8;
    const int i = blockIdx.x * 256 + threadIdx.x;
    const float* s; short* d; int j;
    if (i < NW) { s = Bw; d = Bwbf; j = i; } else { s = Cw; d = Cwbf; j = i - NW; }
    const f32x4 v0 = *(const f32x4*)(s + (size_t)j * 8);
    const f32x4 v1 = *(const f32x4*)(s + (size_t)j * 8 + 4);
    bf16x8 r;
    #pragma unroll
    for (int t = 0; t < 4; ++t) { r[t] = f2bf(v0[t]); r[4 + t] = f2bf(v1[t]); }
    *(bf16x8*)(d + (size_t)j * 8) = r;
}

// ---------------- GEMM1: Bu[m][n] = u[m][:] . Bw[n][:] ----------------
// BM=64, BN=128, BK=64, NT=16. Double-buffered, prefetch-before-compute,
// one barrier per iter. A: fp32 coalesced load -> cvt -> ds_write_b128.
__global__ __launch_bounds__(256) void gemm1(const float* __restrict__ u,
                                             const short* __restrict__ Bwbf,
                                             short* __restrict__ Bu) {
    __shared__ short As[2][8 * 64 * 8];     // [buf][kq 0..7][row 0..63][8]  8KB/buf
    __shared__ short Bs[2][8 * 128 * 8];    // [buf][kq 0..7][row 0..127][8] 16KB/buf
    const int tid = threadIdx.x;
    const int lane = tid & 63, wave = tid >> 6;
    const int lr = lane & 15, kq = lane >> 4;
    const int wr = wave >> 1, wc = wave & 1;
    const int arow = blockIdx.x * 64;
    const int bcol = blockIdx.y * 128;

    // A mapping: row = tid>>2, 16 consecutive floats at k = (tid&3)*16
    const int a_row = tid >> 2, a_c = tid & 3;
    const float* aptr = u + (size_t)(arow + a_row) * D_MODEL + a_c * 16;
    const int aw0 = (a_c * 2) * 512 + a_row * 8;      // [2c][row], 512 = 64*8
    const int aw1 = aw0 + 512;                        // [2c+1][row]

    f32x4 acc[2][4] = {};
    f32x4 areg[4];

    auto loadA = [&](int k0) {
        areg[0] = *(const f32x4*)(aptr + k0);
        areg[1] = *(const f32x4*)(aptr + k0 + 4);
        areg[2] = *(const f32x4*)(aptr + k0 + 8);
        areg[3] = *(const f32x4*)(aptr + k0 + 12);
    };
    auto writeA = [&](int buf) {
        bf16x8 r0, r1;
        #pragma unroll
        for (int t = 0; t < 4; ++t) {
            r0[t] = f2bf(areg[0][t]); r0[4 + t] = f2bf(areg[1][t]);
            r1[t] = f2bf(areg[2][t]); r1[4 + t] = f2bf(areg[3][t]);
        }
        *(bf16x8*)&As[buf][aw0] = r0;
        *(bf16x8*)&As[buf][aw1] = r1;
    };
    auto stageB = [&](int k0, int buf) {
        #pragma unroll
        for (int r = 0; r < 4; ++r) {
            const int slot = r * 256 + tid;           // lane-linear
            const int bkq = slot >> 7, brw = slot & 127;
            GLOAD_LDS16((const char*)Bwbf + ((size_t)(bcol + brw) * D_MODEL + k0 + bkq * 8) * 2,
                        (char*)&Bs[buf][0] + (r * 256 + wave * 64) * 16);
        }
    };
    auto compute = [&](int buf) {
        bf16x8 af[2][2], bfr[2][4];
        #pragma unroll
        for (int s = 0; s < 2; ++s) {
            #pragma unroll
            for (int i = 0; i < 2; ++i)
                af[s][i] = *(const bf16x8*)&As[buf][(s * 4 + kq) * 512 + (wr * 32 + i * 16 + lr) * 8];
            #pragma unroll
            for (int j = 0; j < 4; ++j)
                bfr[s][j] = *(const bf16x8*)&Bs[buf][(s * 4 + kq) * 1024 + (wc * 64 + j * 16 + lr) * 8];
        }
        #pragma unroll
        for (int s = 0; s < 2; ++s)
            #pragma unroll
            for (int i = 0; i < 2; ++i)
                #pragma unroll
                for (int j = 0; j < 4; ++j)
                    acc[i][j] = __builtin_amdgcn_mfma_f32_16x16x32_bf16(bfr[s][j], af[s][i], acc[i][j], 0, 0, 0);
    };

    // prologue: tile 0
    stageB(0, 0);
    loadA(0);
    writeA(0);
    __syncthreads();

    for (int t = 0; t < 16; ++t) {
        const int cur = t & 1;
        if (t < 15) { loadA((t + 1) * 64); stageB((t + 1) * 64, cur ^ 1); }
        compute(cur);
        if (t < 15) writeA(cur ^ 1);
        __syncthreads();
    }

    // swapped-MFMA layout: m = lr, n-regs contiguous -> 8B bf16 vector stores
    #pragma unroll
    for (int i = 0; i < 2; ++i) {
        const int m = arow + wr * 32 + i * 16 + lr;
        #pragma unroll
        for (int j = 0; j < 4; ++j) {
            const int n = bcol + wc * 64 + j * 16 + kq * 4;
            s16x4 st;
            #pragma unroll
            for (int r = 0; r < 4; ++r) st[r] = f2bf(acc[i][j][r]);
            *(s16x4*)(Bu + (size_t)m * STATE_N + n) = st;
        }
    }
}

// ---------------- GEMM2: y[m][d] = h[m][:] . Cw[d][:] + D[d]*u[m][d] ----------------
// BM=128, BN=128, BK=32, NT=8. Double-buffered, one barrier per iter,
// bijective XCD swizzle (each XCD gets contiguous bx range, all by).
__global__ __launch_bounds__(256) void gemm2(const short* __restrict__ hbf,
                                             const short* __restrict__ Cwbf,
                                             const float* __restrict__ u,
                                             const float* __restrict__ Dv,
                                             float* __restrict__ y) {
    __shared__ short As[2][4 * 128 * 8];    // [buf][kq 0..3][row 0..127][8] 8KB/buf
    __shared__ short Bs[2][4 * 128 * 8];
    const int tid = threadIdx.x;
    const int lane = tid & 63, wave = tid >> 6;
    const int lr = lane & 15, kq = lane >> 4;
    const int wr = wave >> 1, wc = wave & 1;
    const int bid = blockIdx.x;
    const int bx = (bid & 7) * 16 + (bid >> 6);   // XCD (bid&7) owns bx in [16*xcd, 16*xcd+16)
    const int by = (bid >> 3) & 7;
    const int arow = bx * 128;
    const int bcol = by * 128;

    auto stage = [&](int k0, int buf) {
        #pragma unroll
        for (int r = 0; r < 2; ++r) {
            const int slot = r * 256 + tid;
            const int skq = slot >> 7, srw = slot & 127;
            GLOAD_LDS16((const char*)hbf + ((size_t)(arow + srw) * STATE_N + k0 + skq * 8) * 2,
                        (char*)&As[buf][0] + (r * 256 + wave * 64) * 16);
            GLOAD_LDS16((const char*)Cwbf + ((size_t)(bcol + srw) * STATE_N + k0 + skq * 8) * 2,
                        (char*)&Bs[buf][0] + (r * 256 + wave * 64) * 16);
        }
    };

    f32x4 acc[4][4] = {};
    stage(0, 0);
    __syncthreads();

    #pragma unroll
    for (int t = 0; t < 8; ++t) {
        const int cur = t & 1;
        if (t < 7) stage((t + 1) * 32, cur ^ 1);
        bf16x8 af[4], bfr[4];
        #pragma unroll
        for (int i = 0; i < 4; ++i)
            af[i]  = *(const bf16x8*)&As[cur][kq * 1024 + (wr * 64 + i * 16 + lr) * 8];
        #pragma unroll
        for (int j = 0; j < 4; ++j)
            bfr[j] = *(const bf16x8*)&Bs[cur][kq * 1024 + (wc * 64 + j * 16 + lr) * 8];
        #pragma unroll
        for (int i = 0; i < 4; ++i)
            #pragma unroll
            for (int j = 0; j < 4; ++j)
                acc[i][j] = __builtin_amdgcn_mfma_f32_16x16x32_bf16(bfr[j], af[i], acc[i][j], 0, 0, 0);
        __syncthreads();
    }

    // m = lr-based row, 4 consecutive n per f32x4 -> vector epilogue
    #pragma unroll
    for (int i = 0; i < 4; ++i) {
        const int m = arow + wr * 64 + i * 16 + lr;
        #pragma unroll
        for (int j = 0; j < 4; ++j) {
            const int n = bcol + wc * 64 + j * 16 + kq * 4;
            const size_t o = (size_t)m * D_MODEL + n;
            const f32x4 uv = *(const f32x4*)(u + o);
            const f32x4 dv = *(const f32x4*)(Dv + n);
            f32x4 rv;
            #pragma unroll
            for (int t = 0; t < 4; ++t) rv[t] = fmaf(dv[t], uv[t], acc[i][j][t]);
            *(f32x4*)(y + o) = rv;
        }
    }
}

// ---------------- Scan pass 1: per-chunk end state ----------------
__global__ void scan_ends(const short* __restrict__ Bu,
                          const float* __restrict__ log_lambda,
                          float* __restrict__ ends) {
    const int n = threadIdx.x;
    const int c = blockIdx.x & (NCHUNK - 1);
    const int b = blockIdx.x >> 7;
    const float lam = sigmoidf(log_lambda[n]);
    float h = 0.0f;
    size_t idx = ((size_t)(b * SEQ_LEN + c * CHUNK)) * STATE_N + n;
    #pragma unroll
    for (int i = 0; i < CHUNK; ++i) { h = fmaf(lam, h, bf2f(Bu[idx])); idx += STATE_N; }
    ends[(size_t)blockIdx.x * STATE_N + n] = h;
}

// ---------------- Scan pass 2: carry scan across chunks ----------------
__global__ void scan_carry(const float* __restrict__ ends,
                           const float* __restrict__ log_lambda,
                           float* __restrict__ carries) {
    const int t = threadIdx.x;                  // 0..1023
    const int n = t & (STATE_N - 1);
    const int b = t >> 8;
    const float lam = sigmoidf(log_lambda[n]);
    const float lamC = powf(lam, (float)CHUNK);
    float carry = 0.0f;
    for (int c = 0; c < NCHUNK; ++c) {
        const size_t o = ((size_t)(b * NCHUNK + c)) * STATE_N + n;
        carries[o] = carry;
        carry = fmaf(lamC, carry, ends[o]);
    }
}

// ---------------- Scan pass 3: seeded scan, write bf16 h ----------------
__global__ void scan_fix(const short* __restrict__ Bu,
                         const float* __restrict__ log_lambda,
                         const float* __restrict__ carries,
                         short* __restrict__ hbf) {
    const int n = threadIdx.x;
    const int c = blockIdx.x & (NCHUNK - 1);
    const int b = blockIdx.x >> 7;
    const float lam = sigmoidf(log_lambda[n]);
    float h = carries[(size_t)blockIdx.x * STATE_N + n];
    size_t idx = ((size_t)(b * SEQ_LEN + c * CHUNK)) * STATE_N + n;
    #pragma unroll
    for (int i = 0; i < CHUNK; ++i) {
        h = fmaf(lam, h, bf2f(Bu[idx]));
        hbf[idx] = f2bf(h);
        idx += STATE_N;
    }
}

extern "C" void kernel_launch(void* const* d_in, const int* in_sizes, int n_in,
                              void* d_out, int out_size, void* d_ws, size_t ws_size,
                              hipStream_t stream) {
    const float* u  = (const float*)d_in[0];
    const float* ll = (const float*)d_in[1];
    const float* Bw = (const float*)d_in[2];
    const float* Cw = (const float*)d_in[3];
    const float* Dv = (const float*)d_in[4];
    float* y = (float*)d_out;

    char* ws = (char*)d_ws;
    size_t off = 0;
    short* Bwbf = (short*)(ws + off); off += (size_t)STATE_N * D_MODEL * 2;
    short* Cwbf = (short*)(ws + off); off += (size_t)D_MODEL * STATE_N * 2;
    short* Bu   = (short*)(ws + off); off += (size_t)M_TOTAL * STATE_N * 2;
    short* hbf  = (short*)(ws + off); off += (size_t)M_TOTAL * STATE_N * 2;
    float* ends = (float*)(ws + off); off += (size_t)BATCH * NCHUNK * STATE_N * 4;
    float* carries = (float*)(ws + off);

    to_bf16_w<<<256, 256, 0, stream>>>(Bw, Cw, Bwbf, Cwbf);
    gemm1<<<dim3(M_TOTAL / 64, STATE_N / 128), 256, 0, stream>>>(u, Bwbf, Bu);
    scan_ends<<<BATCH * NCHUNK, STATE_N, 0, stream>>>(Bu, ll, ends);
    scan_carry<<<1, BATCH * STATE_N, 0, stream>>>(ends, ll, carries);
    scan_fix<<<BATCH * NCHUNK, STATE_N, 0, stream>>>(Bu, ll, carries, hbf);
    gemm2<<<M_TOTAL / 128 * (D_MODEL / 128), 256, 0, stream>>>(hbf, Cwbf, u, Dv, y);
}

// Round 5
// 94.279 us; speedup vs baseline: 2.5139x; 1.0869x over previous
//
#include <hip/hip_runtime.h>

#define D_MODEL 1024
#define STATE_N 256
#define BATCH 4
#define SEQ_LEN 4096
#define M_TOTAL (BATCH * SEQ_LEN)   // 16384
#define NCHUNK 128
#define CHUNK (SEQ_LEN / NCHUNK)    // 32

typedef __attribute__((ext_vector_type(8))) short bf16x8;
typedef __attribute__((ext_vector_type(4))) short s16x4;
typedef __attribute__((ext_vector_type(4))) float f32x4;

static __device__ inline short f2bf(float f) {
    union { float f; unsigned u; } v; v.f = f;
    unsigned r = v.u + 0x7FFFu + ((v.u >> 16) & 1u);
    return (short)(r >> 16);
}
static __device__ inline float bf2f(short s) {
    union { unsigned u; float f; } v;
    v.u = ((unsigned)(unsigned short)s) << 16;
    return v.f;
}
static __device__ inline float sigmoidf(float x) { return 1.0f / (1.0f + expf(-x)); }

#define GLOAD_LDS16(gp, lp)                                                     \
    __builtin_amdgcn_global_load_lds(                                           \
        (const __attribute__((address_space(1))) void*)(gp),                    \
        (__attribute__((address_space(3))) void*)(lp), 16, 0, 0)

#define WAITVM(N) asm volatile("s_waitcnt vmcnt(" #N ")" ::: "memory")
#define WAITLGKM0 asm volatile("s_waitcnt lgkmcnt(0)" ::: "memory")
#define BARRIER() do { __builtin_amdgcn_s_barrier(); asm volatile("" ::: "memory"); } while (0)

// ---------------- tiny pass: Bw, Cw fp32 -> bf16 ----------------
__global__ void to_bf16_w(const float* __restrict__ Bw, const float* __restrict__ Cw,
                          short* __restrict__ Bwbf, short* __restrict__ Cwbf) {
    const int NW = STATE_N * D_MODEL / 8;
    const int i = blockIdx.x * 256 + threadIdx.x;
    const float* s; short* d; int j;
    if (i < NW) { s = Bw; d = Bwbf; j = i; } else { s = Cw; d = Cwbf; j = i - NW; }
    const f32x4 v0 = *(const f32x4*)(s + (size_t)j * 8);
    const f32x4 v1 = *(const f32x4*)(s + (size_t)j * 8 + 4);
    bf16x8 r;
    #pragma unroll
    for (int t = 0; t < 4; ++t) { r[t] = f2bf(v0[t]); r[4 + t] = f2bf(v1[t]); }
    *(bf16x8*)(d + (size_t)j * 8) = r;
}

// ---------------- GEMM1: Bu[m][n] = u[m][:] . Bw[n][:] ----------------
// BM=64, BN=128, BK=64, 16 iters. 3-buffer B (gload_lds, counted vmcnt),
// 2-buffer A (reg-staged fp32->bf16, two alternating reg sets).
__global__ __launch_bounds__(256) void gemm1(const float* __restrict__ u,
                                             const short* __restrict__ Bwbf,
                                             short* __restrict__ Bu) {
    __shared__ short As[2][8 * 64 * 8];     // 8KB per buf: [kq 0..7][row 0..63][8]
    __shared__ short Bs[3][8 * 128 * 8];    // 16KB per buf: [kq 0..7][row 0..127][8]
    const int tid = threadIdx.x;
    const int lane = tid & 63, wave = tid >> 6;
    const int lr = lane & 15, kq = lane >> 4;
    const int wr = wave >> 1, wc = wave & 1;
    const int arow = blockIdx.x * 64;
    const int bcol = blockIdx.y * 128;

    // A mapping: row = tid>>2, 16 consecutive floats at k = (tid&3)*16
    const int a_row = tid >> 2, a_c = tid & 3;
    const float* aptr = u + (size_t)(arow + a_row) * D_MODEL + a_c * 16;
    const int aw0 = (a_c * 2) * 512 + a_row * 8;      // [2c][row]
    const int aw1 = aw0 + 512;

    f32x4 acc[2][4] = {};
    f32x4 ar[2][4];                                    // two alternating A reg sets

    #define LOADA(set, k0)                                                      \
        do { ar[set][0] = *(const f32x4*)(aptr + (k0));                         \
             ar[set][1] = *(const f32x4*)(aptr + (k0) + 4);                     \
             ar[set][2] = *(const f32x4*)(aptr + (k0) + 8);                     \
             ar[set][3] = *(const f32x4*)(aptr + (k0) + 12); } while (0)
    #define WRITEA(buf, set)                                                    \
        do { bf16x8 r0, r1;                                                     \
             _Pragma("unroll")                                                  \
             for (int q = 0; q < 4; ++q) {                                      \
                 r0[q] = f2bf(ar[set][0][q]); r0[4 + q] = f2bf(ar[set][1][q]);  \
                 r1[q] = f2bf(ar[set][2][q]); r1[4 + q] = f2bf(ar[set][3][q]);  \
             }                                                                  \
             *(bf16x8*)&As[buf][aw0] = r0;                                      \
             *(bf16x8*)&As[buf][aw1] = r1; } while (0)
    #define STAGEB(buf, k0)                                                     \
        do { _Pragma("unroll")                                                  \
             for (int r = 0; r < 4; ++r) {                                      \
                 const int slot = r * 256 + tid;                                \
                 const int bkq = slot >> 7, brw = slot & 127;                   \
                 GLOAD_LDS16((const char*)Bwbf +                                \
                     ((size_t)(bcol + brw) * D_MODEL + (k0) + bkq * 8) * 2,     \
                     (char*)&Bs[buf][0] + (r * 256 + wave * 64) * 16);          \
             } } while (0)

    // prologue
    LOADA(0, 0);
    STAGEB(0, 0);
    STAGEB(1, 64);
    LOADA(1, 64);                    // outstanding: A0,B0,B1,A1 (compiler waits A0 below)
    WRITEA(0, 0);
    WAITLGKM0;                       // ds_write of a0 drained before first barrier
    BARRIER();

    #pragma unroll
    for (int t = 0; t < 16; ++t) {
        if (t > 0) {
            if (t < 15) { WAITVM(8); } else { WAITVM(0); }
            BARRIER();
        } else {
            WAITVM(8);               // B0 landed (A0 consumed already)
        }
        if (t + 2 <= 15) {
            STAGEB((t + 2) % 3, (t + 2) * 64);
            LOADA(t & 1, (t + 2) * 64);      // set (t+2)&1 == t&1
        }
        if (t + 1 <= 15) WRITEA((t + 1) & 1, (t + 1) & 1);  // compiler-counted vmcnt wait

        bf16x8 af[2][2], bfr[2][4];
        #pragma unroll
        for (int s = 0; s < 2; ++s) {
            #pragma unroll
            for (int i = 0; i < 2; ++i)
                af[s][i] = *(const bf16x8*)&As[t & 1][(s * 4 + kq) * 512 + (wr * 32 + i * 16 + lr) * 8];
            #pragma unroll
            for (int j = 0; j < 4; ++j)
                bfr[s][j] = *(const bf16x8*)&Bs[t % 3][(s * 4 + kq) * 1024 + (wc * 64 + j * 16 + lr) * 8];
        }
        #pragma unroll
        for (int s = 0; s < 2; ++s)
            #pragma unroll
            for (int i = 0; i < 2; ++i)
                #pragma unroll
                for (int j = 0; j < 4; ++j)
                    acc[i][j] = __builtin_amdgcn_mfma_f32_16x16x32_bf16(bfr[s][j], af[s][i], acc[i][j], 0, 0, 0);
    }

    // swapped-MFMA layout: m = lr, n-regs contiguous -> 8B bf16 vector stores
    #pragma unroll
    for (int i = 0; i < 2; ++i) {
        const int m = arow + wr * 32 + i * 16 + lr;
        #pragma unroll
        for (int j = 0; j < 4; ++j) {
            const int n = bcol + wc * 64 + j * 16 + kq * 4;
            s16x4 st;
            #pragma unroll
            for (int r = 0; r < 4; ++r) st[r] = f2bf(acc[i][j][r]);
            *(s16x4*)(Bu + (size_t)m * STATE_N + n) = st;
        }
    }
    #undef LOADA
    #undef WRITEA
    #undef STAGEB
}

// ---------------- GEMM2: y[m][d] = h[m][:] . Cw[d][:] + D[d]*u[m][d] ----------------
// BM=128, BN=128, BK=32, 8 iters. 3-buffer counted-vmcnt pipeline + XCD swizzle.
__global__ __launch_bounds__(256) void gemm2(const short* __restrict__ hbf,
                                             const short* __restrict__ Cwbf,
                                             const float* __restrict__ u,
                                             const float* __restrict__ Dv,
                                             float* __restrict__ y) {
    __shared__ short As[3][4 * 128 * 8];    // 8KB per buf
    __shared__ short Bs[3][4 * 128 * 8];
    const int tid = threadIdx.x;
    const int lane = tid & 63, wave = tid >> 6;
    const int lr = lane & 15, kq = lane >> 4;
    const int wr = wave >> 1, wc = wave & 1;
    const int bid = blockIdx.x;
    const int bx = (bid & 7) * 16 + (bid >> 6);   // XCD (bid&7) owns contiguous bx range
    const int by = (bid >> 3) & 7;
    const int arow = bx * 128;
    const int bcol = by * 128;

    #define STAGE2(buf, k0)                                                     \
        do { _Pragma("unroll")                                                  \
             for (int r = 0; r < 2; ++r) {                                      \
                 const int slot = r * 256 + tid;                                \
                 const int skq = slot >> 7, srw = slot & 127;                   \
                 GLOAD_LDS16((const char*)hbf +                                 \
                     ((size_t)(arow + srw) * STATE_N + (k0) + skq * 8) * 2,     \
                     (char*)&As[buf][0] + (r * 256 + wave * 64) * 16);          \
                 GLOAD_LDS16((const char*)Cwbf +                                \
                     ((size_t)(bcol + srw) * STATE_N + (k0) + skq * 8) * 2,     \
                     (char*)&Bs[buf][0] + (r * 256 + wave * 64) * 16);          \
             } } while (0)

    f32x4 acc[4][4] = {};
    STAGE2(0, 0);
    STAGE2(1, 32);

    #pragma unroll
    for (int t = 0; t < 8; ++t) {
        if (t < 7) { WAITVM(4); } else { WAITVM(0); }
        BARRIER();
        if (t + 2 <= 7) STAGE2((t + 2) % 3, (t + 2) * 32);

        bf16x8 af[4], bfr[4];
        #pragma unroll
        for (int i = 0; i < 4; ++i)
            af[i]  = *(const bf16x8*)&As[t % 3][kq * 1024 + (wr * 64 + i * 16 + lr) * 8];
        #pragma unroll
        for (int j = 0; j < 4; ++j)
            bfr[j] = *(const bf16x8*)&Bs[t % 3][kq * 1024 + (wc * 64 + j * 16 + lr) * 8];
        #pragma unroll
        for (int i = 0; i < 4; ++i)
            #pragma unroll
            for (int j = 0; j < 4; ++j)
                acc[i][j] = __builtin_amdgcn_mfma_f32_16x16x32_bf16(bfr[j], af[i], acc[i][j], 0, 0, 0);
    }
    #undef STAGE2

    // m = lr-based row, 4 consecutive n per f32x4 -> vector epilogue
    #pragma unroll
    for (int i = 0; i < 4; ++i) {
        const int m = arow + wr * 64 + i * 16 + lr;
        #pragma unroll
        for (int j = 0; j < 4; ++j) {
            const int n = bcol + wc * 64 + j * 16 + kq * 4;
            const size_t o = (size_t)m * D_MODEL + n;
            const f32x4 uv = *(const f32x4*)(u + o);
            const f32x4 dv = *(const f32x4*)(Dv + n);
            f32x4 rv;
            #pragma unroll
            for (int q = 0; q < 4; ++q) rv[q] = fmaf(dv[q], uv[q], acc[i][j][q]);
            *(f32x4*)(y + o) = rv;
        }
    }
}

// ---------------- Scan pass 1: per-chunk end state (wave per chunk, lane owns 4 n) ----------------
__global__ void scan_ends(const short* __restrict__ Bu,
                          const float* __restrict__ log_lambda,
                          float* __restrict__ ends) {
    const int wave = threadIdx.x >> 6, lane = threadIdx.x & 63;
    const int cg = blockIdx.x * 4 + wave;         // global chunk id = b*NCHUNK + c
    const int b = cg >> 7, c = cg & (NCHUNK - 1);
    const int n0 = lane * 4;
    float lam[4], h[4] = {0, 0, 0, 0};
    #pragma unroll
    for (int q = 0; q < 4; ++q) lam[q] = sigmoidf(log_lambda[n0 + q]);
    size_t idx = ((size_t)(b * SEQ_LEN + c * CHUNK)) * STATE_N + n0;
    #pragma unroll
    for (int i = 0; i < CHUNK; ++i) {
        const s16x4 v = *(const s16x4*)(Bu + idx);
        #pragma unroll
        for (int q = 0; q < 4; ++q) h[q] = fmaf(lam[q], h[q], bf2f(v[q]));
        idx += STATE_N;
    }
    f32x4 e; 
    #pragma unroll
    for (int q = 0; q < 4; ++q) e[q] = h[q];
    *(f32x4*)(ends + (size_t)cg * STATE_N + n0) = e;
}

// ---------------- Scan pass 2: carry scan across chunks (per-batch block) ----------------
__global__ void scan_carry(const float* __restrict__ ends,
                           const float* __restrict__ log_lambda,
                           float* __restrict__ carries) {
    const int n = threadIdx.x;
    const int b = blockIdx.x;
    const float lam = sigmoidf(log_lambda[n]);
    const float lamC = powf(lam, (float)CHUNK);
    float carry = 0.0f;
    #pragma unroll 16
    for (int c = 0; c < NCHUNK; ++c) {
        const size_t o = ((size_t)(b * NCHUNK + c)) * STATE_N + n;
        carries[o] = carry;
        carry = fmaf(lamC, carry, ends[o]);
    }
}

// ---------------- Scan pass 3: seeded scan, write bf16 h ----------------
__global__ void scan_fix(const short* __restrict__ Bu,
                         const float* __restrict__ log_lambda,
                         const float* __restrict__ carries,
                         short* __restrict__ hbf) {
    const int wave = threadIdx.x >> 6, lane = threadIdx.x & 63;
    const int cg = blockIdx.x * 4 + wave;
    const int b = cg >> 7, c = cg & (NCHUNK - 1);
    const int n0 = lane * 4;
    float lam[4], h[4];
    #pragma unroll
    for (int q = 0; q < 4; ++q) lam[q] = sigmoidf(log_lambda[n0 + q]);
    const f32x4 cv = *(const f32x4*)(carries + (size_t)cg * STATE_N + n0);
    #pragma unroll
    for (int q = 0; q < 4; ++q) h[q] = cv[q];
    size_t idx = ((size_t)(b * SEQ_LEN + c * CHUNK)) * STATE_N + n0;
    #pragma unroll
    for (int i = 0; i < CHUNK; ++i) {
        const s16x4 v = *(const s16x4*)(Bu + idx);
        s16x4 o;
        #pragma unroll
        for (int q = 0; q < 4; ++q) { h[q] = fmaf(lam[q], h[q], bf2f(v[q])); o[q] = f2bf(h[q]); }
        *(s16x4*)(hbf + idx) = o;
        idx += STATE_N;
    }
}

extern "C" void kernel_launch(void* const* d_in, const int* in_sizes, int n_in,
                              void* d_out, int out_size, void* d_ws, size_t ws_size,
                              hipStream_t stream) {
    const float* u  = (const float*)d_in[0];
    const float* ll = (const float*)d_in[1];
    const float* Bw = (const float*)d_in[2];
    const float* Cw = (const float*)d_in[3];
    const float* Dv = (const float*)d_in[4];
    float* y = (float*)d_out;

    char* ws = (char*)d_ws;
    size_t off = 0;
    short* Bwbf = (short*)(ws + off); off += (size_t)STATE_N * D_MODEL * 2;
    short* Cwbf = (short*)(ws + off); off += (size_t)D_MODEL * STATE_N * 2;
    short* Bu   = (short*)(ws + off); off += (size_t)M_TOTAL * STATE_N * 2;
    short* hbf  = (short*)(ws + off); off += (size_t)M_TOTAL * STATE_N * 2;
    float* ends = (float*)(ws + off); off += (size_t)BATCH * NCHUNK * STATE_N * 4;
    float* carries = (float*)(ws + off);

    to_bf16_w<<<256, 256, 0, stream>>>(Bw, Cw, Bwbf, Cwbf);
    gemm1<<<dim3(M_TOTAL / 64, STATE_N / 128), 256, 0, stream>>>(u, Bwbf, Bu);
    scan_ends<<<BATCH * NCHUNK / 4, 256, 0, stream>>>(Bu, ll, ends);
    scan_carry<<<BATCH, STATE_N, 0, stream>>>(ends, ll, carries);
    scan_fix<<<BATCH * NCHUNK / 4, 256, 0, stream>>>(Bu, ll, carries, hbf);
    gemm2<<<M_TOTAL / 128 * (D_MODEL / 128), 256, 0, stream>>>(hbf, Cwbf, u, Dv, y);
}

// Round 6
// 76.474 us; speedup vs baseline: 3.0992x; 1.2328x over previous
//
#include <hip/hip_runtime.h>
#include <hip/hip_bf16.h>

#define D_MODEL 1024
#define STATE_N 256
#define BATCH 4
#define SEQ_LEN 4096
#define M_TOTAL (BATCH * SEQ_LEN)   // 16384
#define NCHUNK 128
#define CHUNK (SEQ_LEN / NCHUNK)    // 32

typedef __attribute__((ext_vector_type(8))) short bf16x8;
typedef __attribute__((ext_vector_type(4))) short s16x4;
typedef __attribute__((ext_vector_type(4))) float f32x4;

static __device__ inline short f2bf(float f) {
    union { float f; unsigned u; } v; v.f = f;
    unsigned r = v.u + 0x7FFFu + ((v.u >> 16) & 1u);
    return (short)(r >> 16);
}
static __device__ inline short f2bf_hw(float f) {
    __hip_bfloat16 h = __float2bfloat16(f);
    return *reinterpret_cast<const short*>(&h);
}
static __device__ inline float bf2f(short s) {
    union { unsigned u; float f; } v;
    v.u = ((unsigned)(unsigned short)s) << 16;
    return v.f;
}
static __device__ inline float sigmoidf(float x) { return 1.0f / (1.0f + expf(-x)); }

#define GLOAD_LDS16(gp, lp)                                                     \
    __builtin_amdgcn_global_load_lds(                                           \
        (const __attribute__((address_space(1))) void*)(gp),                    \
        (__attribute__((address_space(3))) void*)(lp), 16, 0, 0)

#define WAITVM(N) asm volatile("s_waitcnt vmcnt(" #N ")" ::: "memory")
#define BARRIER() do { __builtin_amdgcn_s_barrier(); asm volatile("" ::: "memory"); } while (0)

// ---------------- weights fp32 -> bf16, TILED layouts ----------------
// Bwt: [cb 2][kt 32][kq 4][col 128][8]  (gemm1 B-tile order)
// Cwt: [cb 16][t 4][ksq 8][col 64][8]   (gemm2 B-tile order)
__global__ void to_bf16_w(const float* __restrict__ Bw, const float* __restrict__ Cw,
                          short* __restrict__ Bwt, short* __restrict__ Cwt) {
    const int g = blockIdx.x * 256 + threadIdx.x;   // grid 256 -> 65536
    const float* s; short* d;
    if (g < 32768) {
        const int col = g & 127, kq = (g >> 7) & 3, kt = (g >> 9) & 31, cb = g >> 14;
        s = Bw + (size_t)(cb * 128 + col) * D_MODEL + kt * 32 + kq * 8;
        d = Bwt + (size_t)g * 8;
    } else {
        const int h = g - 32768;
        const int col = h & 63, ksq = (h >> 6) & 7, t = (h >> 9) & 3, cb = h >> 11;
        s = Cw + (size_t)(cb * 64 + col) * STATE_N + t * 64 + ksq * 8;
        d = Cwt + (size_t)h * 8;
    }
    const f32x4 v0 = *(const f32x4*)s;
    const f32x4 v1 = *(const f32x4*)(s + 4);
    bf16x8 r;
    #pragma unroll
    for (int q = 0; q < 4; ++q) { r[q] = f2bf(v0[q]); r[4 + q] = f2bf(v1[q]); }
    *(bf16x8*)d = r;
}

// ---------------- GEMM1: Bu[m][n] = u[m][:] . Bw[n][:] ----------------
// Block 64r x 128c, BK=32, 32 iters, 3-buffer, counted vmcnt(4), 1 barrier/iter.
// A staged as fp32 [row][32 floats], chunk-XOR swizzled (both sides), cvt at frag read.
__global__ __launch_bounds__(256) void gemm1(const float* __restrict__ u,
                                             const short* __restrict__ Bwt,
                                             short* __restrict__ Bu) {
    __shared__ float As[3][64 * 32];        // 8KB/buf
    __shared__ short Bsh[3][4 * 128 * 8];   // 8KB/buf: [kq][col][8]
    const int tid = threadIdx.x;
    const int lane = tid & 63, wave = tid >> 6;
    const int lr = lane & 15, kq = lane >> 4;
    const int wr = wave >> 1, wc = wave & 1;
    const int wg = ((blockIdx.x & 7) << 6) + (blockIdx.x >> 3);  // 512 = 8*64 bijective
    const int cb = wg & 1, strip = wg >> 1;
    const int m0 = strip * 64, n0 = cb * 128;

    // A staging slots: slot = wave*128 + q*64 + lane; row = slot>>3, chunk = lane&7
    const int aslot0 = wave * 128 + lane, aslot1 = aslot0 + 64;
    const int arow0 = aslot0 >> 3, arow1 = aslot1 >> 3;
    const int ac = lane & 7;
    const float* ag0 = u + (size_t)(m0 + arow0) * D_MODEL + ((ac ^ (arow0 & 7)) << 2);
    const float* ag1 = u + (size_t)(m0 + arow1) * D_MODEL + ((ac ^ (arow1 & 7)) << 2);
    // B staging: slot = wave*128 + q*64 + lane -> [kq=wave][col=q*64+lane]; contiguous global
    const short* bg = Bwt + ((size_t)cb * 32 * 4 + wave) * 128 * 8;

    f32x4 acc[2][4] = {};

    auto STAGE = [&](int buf, int kt) {
        GLOAD_LDS16(ag0 + kt * 32, (char*)&As[buf][0] + aslot0 * 16);
        GLOAD_LDS16(ag1 + kt * 32, (char*)&As[buf][0] + aslot1 * 16);
        const short* bs = bg + (size_t)kt * 4096;
        GLOAD_LDS16(bs + lane * 8,        (char*)&Bsh[buf][0] + (wave * 128 + lane) * 16);
        GLOAD_LDS16(bs + (64 + lane) * 8, (char*)&Bsh[buf][0] + (wave * 128 + 64 + lane) * 16);
    };
    auto COMPUTE = [&](int buf) {
        bf16x8 af[2];
        #pragma unroll
        for (int i = 0; i < 2; ++i) {
            const int row = wr * 32 + i * 16 + lr;
            const f32x4 a0 = *(const f32x4*)&As[buf][row * 32 + (((kq << 1) ^ (row & 7)) << 2)];
            const f32x4 a1 = *(const f32x4*)&As[buf][row * 32 + ((((kq << 1) | 1) ^ (row & 7)) << 2)];
            #pragma unroll
            for (int e = 0; e < 4; ++e) { af[i][e] = f2bf_hw(a0[e]); af[i][4 + e] = f2bf_hw(a1[e]); }
        }
        bf16x8 bfr[4];
        #pragma unroll
        for (int j = 0; j < 4; ++j)
            bfr[j] = *(const bf16x8*)&Bsh[buf][kq * 1024 + (wc * 64 + j * 16 + lr) * 8];
        #pragma unroll
        for (int i = 0; i < 2; ++i)
            #pragma unroll
            for (int j = 0; j < 4; ++j)
                acc[i][j] = __builtin_amdgcn_mfma_f32_16x16x32_bf16(bfr[j], af[i], acc[i][j], 0, 0, 0);
    };

    STAGE(0, 0);
    STAGE(1, 1);
    #pragma unroll
    for (int t = 0; t < 32; ++t) {
        if (t < 31) { WAITVM(4); } else { WAITVM(0); }
        BARRIER();
        if (t + 2 < 32) STAGE((t + 2) % 3, t + 2);
        COMPUTE(t % 3);
    }

    // swapped-MFMA C layout: m = lr-row, 4 consecutive n per f32x4
    #pragma unroll
    for (int i = 0; i < 2; ++i) {
        const int m = m0 + wr * 32 + i * 16 + lr;
        #pragma unroll
        for (int j = 0; j < 4; ++j) {
            const int n = n0 + wc * 64 + j * 16 + kq * 4;
            s16x4 st;
            #pragma unroll
            for (int r = 0; r < 4; ++r) st[r] = f2bf(acc[i][j][r]);
            *(s16x4*)(Bu + (size_t)m * STATE_N + n) = st;
        }
    }
}

// ---------------- GEMM2: y[m][d] = h[m][:] . Cw[d][:] + D[d]*u[m][d] ----------------
// Block 64r x 64c, K=256 staged ENTIRELY up front (4 tiles of BK=64), then
// 4 x {counted vmcnt + barrier + MFMA}. XCD-swizzled grid of 4096.
__global__ __launch_bounds__(256) void gemm2(const short* __restrict__ hbf,
                                             const short* __restrict__ Cwt,
                                             const float* __restrict__ u,
                                             const float* __restrict__ Dv,
                                             float* __restrict__ y) {
    __shared__ short Ash[4][64 * 64];      // 8KB/tile: [row][64 shorts], chunk-XOR
    __shared__ short Bsh[4][8 * 64 * 8];   // 8KB/tile: [ksq][col][8]
    const int tid = threadIdx.x;
    const int lane = tid & 63, wave = tid >> 6;
    const int lr = lane & 15, kq = lane >> 4;
    const int wr = wave >> 1, wc = wave & 1;
    const int wg = ((blockIdx.x & 7) << 9) + (blockIdx.x >> 3);  // 4096 = 8*512 bijective
    const int cb = wg & 15, strip = wg >> 4;
    const int m0 = strip * 64, n0 = cb * 64;

    const int aslot0 = wave * 128 + lane, aslot1 = aslot0 + 64;
    const int arow0 = aslot0 >> 3, arow1 = aslot1 >> 3;
    const int ac = lane & 7;
    const short* ag0 = hbf + (size_t)(m0 + arow0) * STATE_N + ((ac ^ (arow0 & 7)) << 3);
    const short* ag1 = hbf + (size_t)(m0 + arow1) * STATE_N + ((ac ^ (arow1 & 7)) << 3);
    // B: slot = wave*128 + q*64 + lane -> ksq = wave*2+q, col = lane; contiguous global
    const short* bg = Cwt + (size_t)cb * 4 * 8 * 64 * 8;

    // stage all 4 K-tiles up front (16 loads/thread)
    #pragma unroll
    for (int t = 0; t < 4; ++t) {
        GLOAD_LDS16(ag0 + t * 64, (char*)&Ash[t][0] + aslot0 * 16);
        GLOAD_LDS16(ag1 + t * 64, (char*)&Ash[t][0] + aslot1 * 16);
        const short* bs = bg + (size_t)t * 4096;
        GLOAD_LDS16(bs + ((wave * 2 + 0) * 64 + lane) * 8,
                    (char*)&Bsh[t][0] + (wave * 128 + lane) * 16);
        GLOAD_LDS16(bs + ((wave * 2 + 1) * 64 + lane) * 8,
                    (char*)&Bsh[t][0] + (wave * 128 + 64 + lane) * 16);
    }

    f32x4 acc[2][2] = {};
    #pragma unroll
    for (int t = 0; t < 4; ++t) {
        if (t == 0)      { WAITVM(12); }
        else if (t == 1) { WAITVM(8); }
        else if (t == 2) { WAITVM(4); }
        else             { WAITVM(0); }
        BARRIER();
        bf16x8 af[2][2], bfr[2][2];
        #pragma unroll
        for (int ks = 0; ks < 2; ++ks) {
            #pragma unroll
            for (int i = 0; i < 2; ++i) {
                const int row = wr * 32 + i * 16 + lr;
                af[i][ks] = *(const bf16x8*)&Ash[t][row * 64 + ((((ks << 2) | kq) ^ (row & 7)) << 3)];
            }
            #pragma unroll
            for (int j = 0; j < 2; ++j)
                bfr[j][ks] = *(const bf16x8*)&Bsh[t][((ks << 2) | kq) * 512 + (wc * 32 + j * 16 + lr) * 8];
        }
        #pragma unroll
        for (int ks = 0; ks < 2; ++ks)
            #pragma unroll
            for (int i = 0; i < 2; ++i)
                #pragma unroll
                for (int j = 0; j < 2; ++j)
                    acc[i][j] = __builtin_amdgcn_mfma_f32_16x16x32_bf16(bfr[j][ks], af[i][ks], acc[i][j], 0, 0, 0);
    }

    // epilogue: m = lr-row, 4 consecutive n per f32x4 -> vector u/y access
    #pragma unroll
    for (int i = 0; i < 2; ++i) {
        const int m = m0 + wr * 32 + i * 16 + lr;
        #pragma unroll
        for (int j = 0; j < 2; ++j) {
            const int n = n0 + wc * 32 + j * 16 + kq * 4;
            const size_t o = (size_t)m * D_MODEL + n;
            const f32x4 uv = *(const f32x4*)(u + o);
            const f32x4 dv = *(const f32x4*)(Dv + n);
            f32x4 rv;
            #pragma unroll
            for (int q = 0; q < 4; ++q) rv[q] = fmaf(dv[q], uv[q], acc[i][j][q]);
            *(f32x4*)(y + o) = rv;
        }
    }
}

// ---------------- Scan pass 1: per-chunk end state (wave per chunk, lane owns 4 n) ----------------
__global__ void scan_ends(const short* __restrict__ Bu,
                          const float* __restrict__ log_lambda,
                          float* __restrict__ ends) {
    const int wave = threadIdx.x >> 6, lane = threadIdx.x & 63;
    const int cg = blockIdx.x * 4 + wave;
    const int b = cg >> 7, c = cg & (NCHUNK - 1);
    const int n0 = lane * 4;
    float lam[4], h[4] = {0, 0, 0, 0};
    #pragma unroll
    for (int q = 0; q < 4; ++q) lam[q] = sigmoidf(log_lambda[n0 + q]);
    size_t idx = ((size_t)(b * SEQ_LEN + c * CHUNK)) * STATE_N + n0;
    #pragma unroll
    for (int i = 0; i < CHUNK; ++i) {
        const s16x4 v = *(const s16x4*)(Bu + idx);
        #pragma unroll
        for (int q = 0; q < 4; ++q) h[q] = fmaf(lam[q], h[q], bf2f(v[q]));
        idx += STATE_N;
    }
    f32x4 e;
    #pragma unroll
    for (int q = 0; q < 4; ++q) e[q] = h[q];
    *(f32x4*)(ends + (size_t)cg * STATE_N + n0) = e;
}

// ---------------- Scan pass 2: carry scan across chunks ----------------
__global__ void scan_carry(const float* __restrict__ ends,
                           const float* __restrict__ log_lambda,
                           float* __restrict__ carries) {
    const int n = threadIdx.x;
    const int b = blockIdx.x;
    const float lam = sigmoidf(log_lambda[n]);
    const float lamC = powf(lam, (float)CHUNK);
    float carry = 0.0f;
    #pragma unroll 16
    for (int c = 0; c < NCHUNK; ++c) {
        const size_t o = ((size_t)(b * NCHUNK + c)) * STATE_N + n;
        carries[o] = carry;
        carry = fmaf(lamC, carry, ends[o]);
    }
}

// ---------------- Scan pass 3: seeded scan, write bf16 h ----------------
__global__ void scan_fix(const short* __restrict__ Bu,
                         const float* __restrict__ log_lambda,
                         const float* __restrict__ carries,
                         short* __restrict__ hbf) {
    const int wave = threadIdx.x >> 6, lane = threadIdx.x & 63;
    const int cg = blockIdx.x * 4 + wave;
    const int b = cg >> 7, c = cg & (NCHUNK - 1);
    const int n0 = lane * 4;
    float lam[4], h[4];
    #pragma unroll
    for (int q = 0; q < 4; ++q) lam[q] = sigmoidf(log_lambda[n0 + q]);
    const f32x4 cv = *(const f32x4*)(carries + (size_t)cg * STATE_N + n0);
    #pragma unroll
    for (int q = 0; q < 4; ++q) h[q] = cv[q];
    size_t idx = ((size_t)(b * SEQ_LEN + c * CHUNK)) * STATE_N + n0;
    #pragma unroll
    for (int i = 0; i < CHUNK; ++i) {
        const s16x4 v = *(const s16x4*)(Bu + idx);
        s16x4 o;
        #pragma unroll
        for (int q = 0; q < 4; ++q) { h[q] = fmaf(lam[q], h[q], bf2f(v[q])); o[q] = f2bf(h[q]); }
        *(s16x4*)(hbf + idx) = o;
        idx += STATE_N;
    }
}

extern "C" void kernel_launch(void* const* d_in, const int* in_sizes, int n_in,
                              void* d_out, int out_size, void* d_ws, size_t ws_size,
                              hipStream_t stream) {
    const float* u  = (const float*)d_in[0];
    const float* ll = (const float*)d_in[1];
    const float* Bw = (const float*)d_in[2];
    const float* Cw = (const float*)d_in[3];
    const float* Dv = (const float*)d_in[4];
    float* y = (float*)d_out;

    char* ws = (char*)d_ws;
    size_t off = 0;
    short* Bwt = (short*)(ws + off); off += (size_t)STATE_N * D_MODEL * 2;      // 512 KB
    short* Cwt = (short*)(ws + off); off += (size_t)D_MODEL * STATE_N * 2;      // 512 KB
    short* Bu  = (short*)(ws + off); off += (size_t)M_TOTAL * STATE_N * 2;      // 8 MB
    short* hbf = (short*)(ws + off); off += (size_t)M_TOTAL * STATE_N * 2;      // 8 MB
    float* ends = (float*)(ws + off); off += (size_t)BATCH * NCHUNK * STATE_N * 4;
    float* carries = (float*)(ws + off);

    to_bf16_w<<<256, 256, 0, stream>>>(Bw, Cw, Bwt, Cwt);
    gemm1<<<512, 256, 0, stream>>>(u, Bwt, Bu);
    scan_ends<<<BATCH * NCHUNK / 4, 256, 0, stream>>>(Bu, ll, ends);
    scan_carry<<<BATCH, STATE_N, 0, stream>>>(ends, ll, carries);
    scan_fix<<<BATCH * NCHUNK / 4, 256, 0, stream>>>(Bu, ll, carries, hbf);
    gemm2<<<4096, 256, 0, stream>>>(hbf, Cwt, u, Dv, y);
}

// Round 7
// 70.774 us; speedup vs baseline: 3.3488x; 1.0805x over previous
//
#include <hip/hip_runtime.h>
#include <hip/hip_bf16.h>

#define D_MODEL 1024
#define STATE_N 256
#define BATCH 4
#define SEQ_LEN 4096
#define M_TOTAL (BATCH * SEQ_LEN)   // 16384
#define NCHUNK 128
#define CHUNK (SEQ_LEN / NCHUNK)    // 32

typedef __attribute__((ext_vector_type(8))) short bf16x8;
typedef __attribute__((ext_vector_type(4))) short s16x4;
typedef __attribute__((ext_vector_type(4))) float f32x4;

static __device__ inline short f2bf(float f) {
    union { float f; unsigned u; } v; v.f = f;
    unsigned r = v.u + 0x7FFFu + ((v.u >> 16) & 1u);
    return (short)(r >> 16);
}
static __device__ inline float bf2f(short s) {
    union { unsigned u; float f; } v;
    v.u = ((unsigned)(unsigned short)s) << 16;
    return v.f;
}
static __device__ inline float sigmoidf(float x) { return 1.0f / (1.0f + expf(-x)); }

#define GLOAD_LDS16(gp, lp)                                                     \
    __builtin_amdgcn_global_load_lds(                                           \
        (const __attribute__((address_space(1))) void*)(gp),                    \
        (__attribute__((address_space(3))) void*)(lp), 16, 0, 0)

#define WAITVM(N) asm volatile("s_waitcnt vmcnt(" #N ")" ::: "memory")
#define WAITLGKM0 asm volatile("s_waitcnt lgkmcnt(0)" ::: "memory")
#define BARRIER() do { __builtin_amdgcn_s_barrier(); asm volatile("" ::: "memory"); } while (0)

// ---------------- prep: Bw,Cw fp32->bf16 tiled + lambda-power table ----------------
// Bwt: [cb 2][kt 16][kc 8][col 128][8]   (gemm1 B-tile order, BK=64)
// Cwt: [cb 16][t 4][ksq 8][col 64][8]    (gemm2 B-tile order)
// W:   [i 32][n 256] = lam[n]^(31-i)
__global__ void prep(const float* __restrict__ Bw, const float* __restrict__ Cw,
                     const float* __restrict__ ll,
                     short* __restrict__ Bwt, short* __restrict__ Cwt,
                     float* __restrict__ W) {
    const int bx = blockIdx.x, tid = threadIdx.x;
    if (bx >= 256) {   // W table: 32 blocks
        const int i = bx - 256, n = tid;
        W[i * 256 + n] = powf(sigmoidf(ll[n]), (float)(31 - i));
        return;
    }
    const int g = bx * 256 + tid;   // 65536 total
    const float* s; short* d;
    if (g < 32768) {
        const int col = g & 127, kc = (g >> 7) & 7, kt = (g >> 10) & 15, cb = g >> 14;
        s = Bw + (size_t)(cb * 128 + col) * D_MODEL + kt * 64 + kc * 8;
        d = Bwt + (size_t)g * 8;
    } else {
        const int h = g - 32768;
        const int col = h & 63, ksq = (h >> 6) & 7, tt = (h >> 9) & 3, cb = h >> 11;
        s = Cw + (size_t)(cb * 64 + col) * STATE_N + tt * 64 + ksq * 8;
        d = Cwt + (size_t)h * 8;
    }
    const f32x4 v0 = *(const f32x4*)s;
    const f32x4 v1 = *(const f32x4*)(s + 4);
    bf16x8 r;
    #pragma unroll
    for (int q = 0; q < 4; ++q) { r[q] = f2bf(v0[q]); r[4 + q] = f2bf(v1[q]); }
    *(bf16x8*)d = r;
}

// ---------------- GEMM1: Bu[m][n] = u[m][:].Bw[n][:], fused chunk-end scan ----------------
// BM=64, BN=128, BK=64, 16 iters. A reg-staged fp32->bf16 (3 reg sets, ds_write
// after barrier), B gload_lds from tiled Bwt (3 LDS bufs). Counted vmcnt: issue
// at t for t+2/t+3, steady WAITVM(8). Epilogue: swapped-MFMA vector Bu stores +
// lam-weighted shfl reduce -> ends.
__global__ __launch_bounds__(256, 2) void gemm1(const float* __restrict__ u,
                                                const short* __restrict__ Bwt,
                                                const float* __restrict__ W,
                                                short* __restrict__ Bu,
                                                float* __restrict__ ends) {
    __shared__ short Ash[2][64 * 64];       // 8KB/buf: [row][8 chunks of 8, XOR-swz]
    __shared__ short Bsh[3][8 * 128 * 8];   // 16KB/buf: [kc][col][8]
    const int tid = threadIdx.x;
    const int lane = tid & 63, wave = tid >> 6;
    const int lr = lane & 15, kq = lane >> 4;
    const int wr = wave >> 1, wc = wave & 1;
    const int wg = ((blockIdx.x & 7) << 6) + (blockIdx.x >> 3);  // 512 = 8*64 bijective
    const int cb = wg & 1, strip = wg >> 1;
    const int m0 = strip * 64, n0 = cb * 128;

    // A: instr i covers rows [i*16, i*16+16); thread reads 4 consecutive floats
    const int a_r = tid >> 4, a_k = (tid & 15) * 4;
    const float* au = u + (size_t)m0 * D_MODEL + (size_t)a_r * D_MODEL + a_k;
    // A ds_write target pieces: row = i*16 + a_r, chunk = a_k>>3, halfoff = (tid&1)*4 shorts
    const int a_ch = (tid & 15) >> 1, a_half = (tid & 1) * 4;
    // B: pre-tiled source, 16KB per (cb, kt)
    const short* bg = Bwt + (size_t)cb * 16 * 8192;

    f32x4 acc[2][4] = {};
    f32x4 ar0[4], ar1[4], ar2[4];           // 3 A register sets

    #define LOADA(SET, KT)                                                       \
        do { _Pragma("unroll")                                                   \
             for (int i = 0; i < 4; ++i)                                         \
                 SET[i] = *(const f32x4*)(au + (size_t)i * 16 * D_MODEL + (KT) * 64); } while (0)
    #define WRITEA(BUF, SET)                                                     \
        do { _Pragma("unroll")                                                   \
             for (int i = 0; i < 4; ++i) {                                       \
                 const int row = i * 16 + a_r;                                   \
                 s16x4 wv;                                                       \
                 _Pragma("unroll")                                               \
                 for (int e = 0; e < 4; ++e) wv[e] = f2bf(SET[i][e]);            \
                 *(s16x4*)&Ash[BUF][(row * 8 + (a_ch ^ (row & 7))) * 8 + a_half] = wv; \
             } } while (0)
    #define STAGEB(BUF, KT)                                                      \
        do { const short* bs = bg + (size_t)(KT) * 8192;                         \
             _Pragma("unroll")                                                   \
             for (int q = 0; q < 4; ++q)                                         \
                 GLOAD_LDS16(bs + (q * 256 + tid) * 8,                           \
                             (char*)&Bsh[BUF][0] + (q * 256 + wave * 64) * 16); } while (0)

    // prologue: A(0) direct, then B(0),A(1),B(1),A(2) in this exact order
    LOADA(ar0, 0);
    WAITVM(0);
    WRITEA(0, ar0);
    STAGEB(0, 0);
    LOADA(ar1, 1);
    STAGEB(1, 1);
    LOADA(ar2, 2);
    WAITLGKM0;

    #pragma unroll
    for (int t = 0; t < 16; ++t) {
        if (t < 14)      { WAITVM(8); }   // drains B(t), A(t+1)-regs
        else if (t == 14){ WAITVM(4); }
        else             { WAITVM(0); }
        BARRIER();
        if (t < 15) {                      // ds_write A(t+1) (post-barrier: no race)
            if (((t + 1) % 3) == 0)      WRITEA((t + 1) & 1, ar0);
            else if (((t + 1) % 3) == 1) WRITEA((t + 1) & 1, ar1);
            else                         WRITEA((t + 1) & 1, ar2);
        }
        // fragment reads (t)
        bf16x8 af[2][2], bfr[2][4];
        #pragma unroll
        for (int ks = 0; ks < 2; ++ks) {
            #pragma unroll
            for (int i = 0; i < 2; ++i) {
                const int row = wr * 32 + i * 16 + lr;
                af[ks][i] = *(const bf16x8*)&Ash[t & 1][(row * 8 + ((ks * 4 + kq) ^ (row & 7))) * 8];
            }
            #pragma unroll
            for (int j = 0; j < 4; ++j)
                bfr[ks][j] = *(const bf16x8*)&Bsh[t % 3][((ks * 4 + kq) * 128 + wc * 64 + j * 16 + lr) * 8];
        }
        // prefetch issues for t+2 / t+3
        if (t + 2 <= 15) STAGEB((t + 2) % 3, t + 2);
        if (t + 3 <= 15) {
            if (((t + 3) % 3) == 0)      LOADA(ar0, t + 3);
            else if (((t + 3) % 3) == 1) LOADA(ar1, t + 3);
            else                         LOADA(ar2, t + 3);
        }
        #pragma unroll
        for (int ks = 0; ks < 2; ++ks)
            #pragma unroll
            for (int i = 0; i < 2; ++i)
                #pragma unroll
                for (int j = 0; j < 4; ++j)
                    acc[i][j] = __builtin_amdgcn_mfma_f32_16x16x32_bf16(bfr[ks][j], af[ks][i], acc[i][j], 0, 0, 0);
    }
    #undef LOADA
    #undef WRITEA
    #undef STAGEB

    // ---- Bu stores (swapped layout: m=lr-row, 4 consecutive n per f32x4) ----
    #pragma unroll
    for (int i = 0; i < 2; ++i) {
        const int m = m0 + wr * 32 + i * 16 + lr;
        #pragma unroll
        for (int j = 0; j < 4; ++j) {
            const int n = n0 + wc * 64 + j * 16 + kq * 4;
            s16x4 st;
            #pragma unroll
            for (int r = 0; r < 4; ++r) st[r] = f2bf(acc[i][j][r]);
            *(s16x4*)(Bu + (size_t)m * STATE_N + n) = st;
        }
    }

    // ---- fused chunk-end reduce: ends[cg][n] = sum_row lam^(31-row)*Bu ----
    float part[4][4];
    #pragma unroll
    for (int j = 0; j < 4; ++j) {
        const int nb = n0 + wc * 64 + j * 16 + kq * 4;
        const f32x4 w0 = *(const f32x4*)(W + (size_t)lr * 256 + nb);
        const f32x4 w1 = *(const f32x4*)(W + (size_t)(16 + lr) * 256 + nb);
        #pragma unroll
        for (int r = 0; r < 4; ++r)
            part[j][r] = w0[r] * acc[0][j][r] + w1[r] * acc[1][j][r];
    }
    #pragma unroll
    for (int m = 1; m <= 8; m <<= 1)
        #pragma unroll
        for (int j = 0; j < 4; ++j)
            #pragma unroll
            for (int r = 0; r < 4; ++r)
                part[j][r] += __shfl_xor(part[j][r], m, 64);
    if (lr == 0) {
        const int cg = strip * 2 + wr;
        #pragma unroll
        for (int j = 0; j < 4; ++j) {
            f32x4 e;
            #pragma unroll
            for (int r = 0; r < 4; ++r) e[r] = part[j][r];
            *(f32x4*)(ends + (size_t)cg * STATE_N + n0 + wc * 64 + j * 16 + kq * 4) = e;
        }
    }
}

// ---------------- GEMM2: y[m][d] = h[m][:].Cw[d][:] + D[d]*u[m][d] ----------------
// Block 64r x 64c, K=256 staged entirely up front, 4 x {counted vmcnt + barrier + MFMA}.
__global__ __launch_bounds__(256) void gemm2(const short* __restrict__ hbf,
                                             const short* __restrict__ Cwt,
                                             const float* __restrict__ u,
                                             const float* __restrict__ Dv,
                                             float* __restrict__ y) {
    __shared__ short Ash[4][64 * 64];
    __shared__ short Bsh[4][8 * 64 * 8];
    const int tid = threadIdx.x;
    const int lane = tid & 63, wave = tid >> 6;
    const int lr = lane & 15, kq = lane >> 4;
    const int wr = wave >> 1, wc = wave & 1;
    const int wg = ((blockIdx.x & 7) << 9) + (blockIdx.x >> 3);  // 4096 = 8*512 bijective
    const int cb = wg & 15, strip = wg >> 4;
    const int m0 = strip * 64, n0 = cb * 64;

    const int aslot0 = wave * 128 + lane, aslot1 = aslot0 + 64;
    const int arow0 = aslot0 >> 3, arow1 = aslot1 >> 3;
    const int ac = lane & 7;
    const short* ag0 = hbf + (size_t)(m0 + arow0) * STATE_N + ((ac ^ (arow0 & 7)) << 3);
    const short* ag1 = hbf + (size_t)(m0 + arow1) * STATE_N + ((ac ^ (arow1 & 7)) << 3);
    const short* bg = Cwt + (size_t)cb * 4 * 8 * 64 * 8;

    #pragma unroll
    for (int t = 0; t < 4; ++t) {
        GLOAD_LDS16(ag0 + t * 64, (char*)&Ash[t][0] + aslot0 * 16);
        GLOAD_LDS16(ag1 + t * 64, (char*)&Ash[t][0] + aslot1 * 16);
        const short* bs = bg + (size_t)t * 4096;
        GLOAD_LDS16(bs + ((wave * 2 + 0) * 64 + lane) * 8,
                    (char*)&Bsh[t][0] + (wave * 128 + lane) * 16);
        GLOAD_LDS16(bs + ((wave * 2 + 1) * 64 + lane) * 8,
                    (char*)&Bsh[t][0] + (wave * 128 + 64 + lane) * 16);
    }

    f32x4 acc[2][2] = {};
    #pragma unroll
    for (int t = 0; t < 4; ++t) {
        if (t == 0)      { WAITVM(12); }
        else if (t == 1) { WAITVM(8); }
        else if (t == 2) { WAITVM(4); }
        else             { WAITVM(0); }
        BARRIER();
        bf16x8 af[2][2], bfr[2][2];
        #pragma unroll
        for (int ks = 0; ks < 2; ++ks) {
            #pragma unroll
            for (int i = 0; i < 2; ++i) {
                const int row = wr * 32 + i * 16 + lr;
                af[i][ks] = *(const bf16x8*)&Ash[t][row * 64 + ((((ks << 2) | kq) ^ (row & 7)) << 3)];
            }
            #pragma unroll
            for (int j = 0; j < 2; ++j)
                bfr[j][ks] = *(const bf16x8*)&Bsh[t][((ks << 2) | kq) * 512 + (wc * 32 + j * 16 + lr) * 8];
        }
        #pragma unroll
        for (int ks = 0; ks < 2; ++ks)
            #pragma unroll
            for (int i = 0; i < 2; ++i)
                #pragma unroll
                for (int j = 0; j < 2; ++j)
                    acc[i][j] = __builtin_amdgcn_mfma_f32_16x16x32_bf16(bfr[j][ks], af[i][ks], acc[i][j], 0, 0, 0);
    }

    #pragma unroll
    for (int i = 0; i < 2; ++i) {
        const int m = m0 + wr * 32 + i * 16 + lr;
        #pragma unroll
        for (int j = 0; j < 2; ++j) {
            const int n = n0 + wc * 32 + j * 16 + kq * 4;
            const size_t o = (size_t)m * D_MODEL + n;
            const f32x4 uv = *(const f32x4*)(u + o);
            const f32x4 dv = *(const f32x4*)(Dv + n);
            f32x4 rv;
            #pragma unroll
            for (int q = 0; q < 4; ++q) rv[q] = fmaf(dv[q], uv[q], acc[i][j][q]);
            *(f32x4*)(y + o) = rv;
        }
    }
}

// ---------------- Scan pass 2: carry scan across chunks ----------------
__global__ void scan_carry(const float* __restrict__ ends,
                           const float* __restrict__ log_lambda,
                           float* __restrict__ carries) {
    const int n = threadIdx.x;
    const int b = blockIdx.x;
    const float lam = sigmoidf(log_lambda[n]);
    const float lamC = powf(lam, (float)CHUNK);
    float carry = 0.0f;
    #pragma unroll 16
    for (int c = 0; c < NCHUNK; ++c) {
        const size_t o = ((size_t)(b * NCHUNK + c)) * STATE_N + n;
        carries[o] = carry;
        carry = fmaf(lamC, carry, ends[o]);
    }
}

// ---------------- Scan pass 3: seeded scan, write bf16 h ----------------
__global__ void scan_fix(const short* __restrict__ Bu,
                         const float* __restrict__ log_lambda,
                         const float* __restrict__ carries,
                         short* __restrict__ hbf) {
    const int wave = threadIdx.x >> 6, lane = threadIdx.x & 63;
    const int cg = blockIdx.x * 4 + wave;
    const int b = cg >> 7, c = cg & (NCHUNK - 1);
    const int n0 = lane * 4;
    float lam[4], h[4];
    #pragma unroll
    for (int q = 0; q < 4; ++q) lam[q] = sigmoidf(log_lambda[n0 + q]);
    const f32x4 cv = *(const f32x4*)(carries + (size_t)cg * STATE_N + n0);
    #pragma unroll
    for (int q = 0; q < 4; ++q) h[q] = cv[q];
    size_t idx = ((size_t)(b * SEQ_LEN + c * CHUNK)) * STATE_N + n0;
    #pragma unroll
    for (int i = 0; i < CHUNK; ++i) {
        const s16x4 v = *(const s16x4*)(Bu + idx);
        s16x4 o;
        #pragma unroll
        for (int q = 0; q < 4; ++q) { h[q] = fmaf(lam[q], h[q], bf2f(v[q])); o[q] = f2bf(h[q]); }
        *(s16x4*)(hbf + idx) = o;
        idx += STATE_N;
    }
}

extern "C" void kernel_launch(void* const* d_in, const int* in_sizes, int n_in,
                              void* d_out, int out_size, void* d_ws, size_t ws_size,
                              hipStream_t stream) {
    const float* u  = (const float*)d_in[0];
    const float* ll = (const float*)d_in[1];
    const float* Bw = (const float*)d_in[2];
    const float* Cw = (const float*)d_in[3];
    const float* Dv = (const float*)d_in[4];
    float* y = (float*)d_out;

    char* ws = (char*)d_ws;
    size_t off = 0;
    short* Bwt = (short*)(ws + off); off += (size_t)STATE_N * D_MODEL * 2;      // 512 KB
    short* Cwt = (short*)(ws + off); off += (size_t)D_MODEL * STATE_N * 2;      // 512 KB
    float* W   = (float*)(ws + off); off += (size_t)32 * STATE_N * 4;           // 32 KB
    short* Bu  = (short*)(ws + off); off += (size_t)M_TOTAL * STATE_N * 2;      // 8 MB
    short* hbf = (short*)(ws + off); off += (size_t)M_TOTAL * STATE_N * 2;      // 8 MB
    float* ends = (float*)(ws + off); off += (size_t)BATCH * NCHUNK * STATE_N * 4;
    float* carries = (float*)(ws + off);

    prep<<<288, 256, 0, stream>>>(Bw, Cw, ll, Bwt, Cwt, W);
    gemm1<<<512, 256, 0, stream>>>(u, Bwt, W, Bu, ends);
    scan_carry<<<BATCH, STATE_N, 0, stream>>>(ends, ll, carries);
    scan_fix<<<BATCH * NCHUNK / 4, 256, 0, stream>>>(Bu, ll, carries, hbf);
    gemm2<<<4096, 256, 0, stream>>>(hbf, Cwt, u, Dv, y);
}